// Round 6
// baseline (1605.650 us; speedup 1.0000x reference)
//
#include <hip/hip_runtime.h>
#include <cstdint>

#define NTOK 2048
#define DMODEL 1024
#define NHEADS 16
#define HD 64
#define BATCH 2
#define EPSF 1e-10f
#define EPSD 1e-10

typedef __attribute__((ext_vector_type(8))) short bf16x8;
typedef __attribute__((ext_vector_type(8))) _Float16 f16x8;
typedef __attribute__((ext_vector_type(4))) float f32x4;

__device__ __forceinline__ float bf2f(unsigned short u){
  union { unsigned int i; float f; } c; c.i = ((unsigned int)u) << 16; return c.f;
}
__device__ __forceinline__ unsigned short f2bf(float f){
  union { float f; unsigned int u; } c; c.f = f;
  unsigned int u = c.u;
  unsigned int r = (u + 0x7FFFu + ((u >> 16) & 1u)) >> 16;
  return (unsigned short)r;
}
__device__ __forceinline__ unsigned short f2h(float f){
  union { _Float16 h; unsigned short u; } c; c.h = (_Float16)f; return c.u;
}

__device__ __forceinline__ void async16(const unsigned short* g, unsigned short* lds_base){
  __builtin_amdgcn_global_load_lds((const __attribute__((address_space(1))) unsigned int*)g,
                                   (__attribute__((address_space(3))) unsigned int*)lds_base,
                                   16, 0, 0);
}

// C[m,n] = sum_k A[m,k] * B[n,k]  (both K-major bf16), 256 threads, waves 2x2.
template<int BM, int BN>
__device__ __forceinline__ void gemm_bt_core(
    const unsigned short* A, int lda,
    const unsigned short* B, int ldb,
    int K,
    f32x4 (&acc)[BM/32][BN/32],
    unsigned short* ldsA, unsigned short* ldsB)
{
  constexpr int TM = BM/32, TN = BN/32;
  const int tid  = threadIdx.x;
  const int lane = tid & 63;
  const int wave = tid >> 6;
  const int wm = wave >> 1, wn = wave & 1;
  const int fr = lane & 15;
  const int fk = (lane >> 4) << 3;
  const int sr = lane >> 2;
  const int sk = (lane & 3) << 3;

  for (int k0 = 0; k0 < K; k0 += 32){
    #pragma unroll
    for (int c = 0; c < BM/64; c++){
      int ch = c*4 + wave;
      async16(A + (long)(ch*16 + sr)*lda + (k0 + sk), ldsA + ch*512);
    }
    #pragma unroll
    for (int c = 0; c < BN/64; c++){
      int ch = c*4 + wave;
      async16(B + (long)(ch*16 + sr)*ldb + (k0 + sk), ldsB + ch*512);
    }
    __syncthreads();
    bf16x8 af[TM], bf[TN];
    #pragma unroll
    for (int i=0;i<TM;i++)
      af[i] = *(const bf16x8*)(ldsA + ((wm*TM*16) + i*16 + fr)*32 + fk);
    #pragma unroll
    for (int j=0;j<TN;j++)
      bf[j] = *(const bf16x8*)(ldsB + ((wn*TN*16) + j*16 + fr)*32 + fk);
    #pragma unroll
    for (int i=0;i<TM;i++)
      #pragma unroll
      for (int j=0;j<TN;j++)
        acc[i][j] = __builtin_amdgcn_mfma_f32_16x16x32_bf16(af[i], bf[j], acc[i][j], 0, 0, 0);
    __syncthreads();
  }
}

__device__ __forceinline__ double wred_sumd(double x){
  for(int o=32;o;o>>=1) x+=__shfl_xor(x,o); return x;
}

// grid-wide barrier for the persistent sinkhorn kernel (all blocks resident)
__device__ __forceinline__ void gbar(int* bar, int target){
  __threadfence();                 // release my stores to device scope
  __syncthreads();                 // whole block fenced
  if (threadIdx.x == 0){
    atomicAdd(bar, 1);
    while (atomicAdd(bar, 0) < target) __builtin_amdgcn_s_sleep(2);
  }
  __syncthreads();
  __threadfence();                 // acquire: don't read stale lines
}

// ---------------- kernels ----------------

__global__ void f2b_kernel(const float* __restrict__ in, unsigned short* __restrict__ out, int n){
  int i = blockIdx.x*256 + threadIdx.x;
  if (i < n) out[i] = f2bf(in[i]);
}

__global__ void init_kernel(double* __restrict__ uv, int* __restrict__ bar){
  int idx = blockIdx.x*256 + threadIdx.x;
  if (idx < 8192) uv[idx] = 1.0;     // u, v
  if (idx == 0) bar[0] = 0;
}

__global__ __launch_bounds__(256) void qkv_kernel(
    const unsigned short* __restrict__ xb,
    const unsigned short* __restrict__ Wqb, const float* __restrict__ bq,
    const unsigned short* __restrict__ Wkb, const float* __restrict__ bk,
    const unsigned short* __restrict__ Wvb, const float* __restrict__ bv,
    unsigned short* __restrict__ Qb, unsigned short* __restrict__ Kb,
    unsigned short* __restrict__ Vb)
{
  __shared__ unsigned short lds[(128+128)*32];
  int sel = blockIdx.y >> 3;
  int n0 = (blockIdx.y & 7) * 128;
  int m0 = blockIdx.x * 128;
  const unsigned short* W = sel==0 ? Wqb : (sel==1 ? Wkb : Wvb);
  const float* bias       = sel==0 ? bq  : (sel==1 ? bk  : bv);
  unsigned short* out     = sel==0 ? Qb  : (sel==1 ? Kb  : Vb);
  f32x4 acc[4][4];
  f32x4 z = {0.f,0.f,0.f,0.f};
  for (int i=0;i<4;i++) for(int j=0;j<4;j++) acc[i][j] = z;
  gemm_bt_core<128,128>(xb + (long)m0*DMODEL, DMODEL, W + (long)n0*DMODEL, DMODEL,
                        DMODEL, acc, lds, lds + 128*32);
  int lane = threadIdx.x & 63, wave = threadIdx.x >> 6;
  int wm = wave>>1, wn = wave&1;
  int cr = (lane>>4)<<2, cc = lane & 15;
  for (int i=0;i<4;i++) for(int j=0;j<4;j++) for(int r=0;r<4;r++){
    int row = m0 + wm*64 + i*16 + cr + r;
    int col = n0 + wn*64 + j*16 + cc;
    out[(long)row*DMODEL + col] = f2bf(acc[i][j][r] + bias[col]);
  }
}

__global__ void vtrans_kernel(const unsigned short* __restrict__ Vb,
                              unsigned short* __restrict__ Vt)
{
  __shared__ unsigned short t[32][33];
  int b = blockIdx.z, i0 = blockIdx.x*32, e0 = blockIdx.y*32;
  int tx = threadIdx.x, ty = threadIdx.y;
  for (int r=0;r<32;r+=8) t[ty+r][tx] = Vb[((long)b*NTOK + i0+ty+r)*DMODEL + e0+tx];
  __syncthreads();
  for (int r=0;r<32;r+=8) Vt[((long)b*DMODEL + e0+ty+r)*NTOK + i0+tx] = t[tx][ty+r];
}

// f32 per-batch transpose (for sinkhorn column pass)
__global__ void ftrans_kernel(const float* __restrict__ in, float* __restrict__ out){
  __shared__ float t[32][33];
  int b = blockIdx.z, i0 = blockIdx.x*32, j0 = blockIdx.y*32;
  int tx = threadIdx.x, ty = threadIdx.y;
  for (int r=0;r<32;r+=8) t[ty+r][tx] = in[((long)(b*NTOK + i0+ty+r))*NTOK + j0+tx];
  __syncthreads();
  for (int r=0;r<32;r+=8) out[((long)(b*NTOK + j0+ty+r))*NTOK + i0+tx] = t[tx][ty+r];
}

// ---- single-pass flash attention per (b,h,row-block)  [round-4 verbatim] ----
__global__ __launch_bounds__(256,2) void attnA_kernel(
    const unsigned short* __restrict__ Qb, const unsigned short* __restrict__ Kb,
    const unsigned short* __restrict__ Vt, const int* __restrict__ perm,
    const float* __restrict__ psc,
    unsigned short* __restrict__ Ob, float* __restrict__ mbuf,
    float* __restrict__ ilbuf, float* __restrict__ entb,
    float* __restrict__ mscale, unsigned short* __restrict__ Pbig,
    int h0, int gcnt)
{
  __shared__ unsigned short Kt[2*128*32];   // bf16 [kc][row][32]
  __shared__ unsigned short Vtl[64*136];    // f16  [ocol][128+pad]
  __shared__ unsigned short Pt[128*136];    // f16  [row][128+pad]
  __shared__ unsigned short pbs[2048];

  const int tid  = threadIdx.x;
  const int lane = tid & 63;
  const int wave = tid >> 6;
  const int fr   = lane & 15;
  const int fkg  = lane >> 4;
  const int fk   = fkg << 3;
  const int cr   = fkg << 2;
  const int m0   = blockIdx.x * 128;
  const int hl   = blockIdx.y;
  const int h    = h0 + hl;
  const int b    = blockIdx.z;

  for (int i = tid; i < 2048; i += 256) pbs[i] = (unsigned short)perm[b*NTOK + i];

  bf16x8 qf[2][2];
  #pragma unroll
  for (int i=0;i<2;i++)
    #pragma unroll
    for (int kc=0;kc<2;kc++)
      qf[i][kc] = *(const bf16x8*)(Qb + ((long)(b*NTOK + m0 + wave*32 + i*16 + fr))*DMODEL + h*HD + kc*32 + fk);

  const float asc = fabsf(psc[h]);
  __syncthreads();

  float prow[2][4];
  #pragma unroll
  for (int i=0;i<2;i++)
    #pragma unroll
    for (int r=0;r<4;r++)
      prow[i][r] = (float)pbs[m0 + wave*32 + i*16 + cr + r];

  float mrow[2][4], lrow[2][4], Trow[2][4];
  #pragma unroll
  for (int i=0;i<2;i++) for(int r=0;r<4;r++){ mrow[i][r] = -1e30f; lrow[i][r] = 0.f; Trow[i][r] = 0.f; }
  f32x4 oacc[2][4];
  {
    f32x4 z = {0.f,0.f,0.f,0.f};
    for (int i=0;i<2;i++) for(int jj=0;jj<4;jj++) oacc[i][jj]=z;
  }

  for (int j=0;j<16;j++){
    __syncthreads();           // protect Kt/Vtl/Pt reuse across iterations
    #pragma unroll
    for (int c=0;c<4;c++){
      int q = wave*4 + c;
      int kc = q >> 3, rb = (q & 7) * 16;
      async16(Kb + ((long)(b*NTOK + j*128 + rb + (lane>>2)))*DMODEL + h*HD + kc*32 + ((lane&3)<<3),
              Kt + kc*4096 + rb*32);
    }
    {   // V tile: bf16 global -> f16 LDS
      int c = tid>>2, sg = tid&3;
      const unsigned short* vg = Vt + ((long)(b*DMODEL + h*HD + c))*NTOK + j*128 + sg*32;
      unsigned short* vl = Vtl + c*136 + sg*32;
      #pragma unroll
      for (int s2=0;s2<4;s2++){
        bf16x8 vv = *(const bf16x8*)(vg + s2*8);
        unsigned short tmp[8];
        #pragma unroll
        for (int e=0;e<8;e++) tmp[e] = f2h(bf2f(((unsigned short*)&vv)[e]));
        *(uint4*)(vl + s2*8) = *(uint4*)tmp;
      }
    }
    __syncthreads();

    f32x4 sacc[2][8];
    {
      f32x4 z = {0.f,0.f,0.f,0.f};
      for (int i=0;i<2;i++) for(int jj=0;jj<8;jj++) sacc[i][jj]=z;
    }
    #pragma unroll
    for (int kc=0;kc<2;kc++){
      bf16x8 bfr[8];
      #pragma unroll
      for (int jj=0;jj<8;jj++) bfr[jj] = *(const bf16x8*)(Kt + kc*4096 + (jj*16+fr)*32 + fk);
      #pragma unroll
      for (int i=0;i<2;i++)
        #pragma unroll
        for (int jj=0;jj<8;jj++)
          sacc[i][jj] = __builtin_amdgcn_mfma_f32_16x16x32_bf16(qf[i][kc], bfr[jj], sacc[i][jj],0,0,0);
    }

    float pcol[8];
    #pragma unroll
    for (int jj=0;jj<8;jj++) pcol[jj] = (float)pbs[j*128 + jj*16 + fr];

    #pragma unroll
    for (int i=0;i<2;i++)
      #pragma unroll
      for (int r=0;r<4;r++){
        float sv[8];
        float tm = -1e30f;
        #pragma unroll
        for (int jj=0;jj<8;jj++){
          sv[jj] = sacc[i][jj][r]*0.125f - fabsf(prow[i][r]-pcol[jj])*asc;
          tm = fmaxf(tm, sv[jj]);
        }
        #pragma unroll
        for (int o=1;o<16;o<<=1) tm = fmaxf(tm, __shfl_xor(tm,o));
        float nm = fmaxf(mrow[i][r], tm);
        float alpha = expf(mrow[i][r] - nm);
        float lres = lrow[i][r]*alpha;
        Trow[i][r] = Trow[i][r]*alpha + (mrow[i][r]-nm)*lres;
        #pragma unroll
        for (int jc=0;jc<4;jc++) oacc[i][jc][r] *= alpha;
        float ts=0.f, tT=0.f;
        int prowbase = (wave*32 + i*16 + cr + r)*136;
        #pragma unroll
        for (int jj=0;jj<8;jj++){
          float d = sv[jj]-nm;
          float ev = expf(d);
          ts += ev; tT += ev*d;
          Pt[prowbase + jj*16 + fr] = f2h(ev);
        }
        #pragma unroll
        for (int o=1;o<16;o<<=1){ ts += __shfl_xor(ts,o); tT += __shfl_xor(tT,o); }
        lrow[i][r] = lres + ts;
        Trow[i][r] += tT;
        mrow[i][r] = nm;
        if (fr==0)
          mscale[(((long)(b*NHEADS+h))*16 + j)*NTOK + m0 + wave*32 + i*16 + cr + r] = nm;
      }
    __syncthreads();
    {   // coalesced P tile spill (f16)
      const uint4* src = (const uint4*)(Pt + (tid>>1)*136 + (tid&1)*64);
      uint4* dst = (uint4*)(Pbig + (((long)(b*gcnt + hl)*NTOK + m0 + (tid>>1)))*NTOK + j*128 + (tid&1)*64);
      #pragma unroll
      for (int q=0;q<8;q++) dst[q] = src[q];
    }
    #pragma unroll
    for (int kp=0;kp<4;kp++){
      f16x8 paf[2], pbf[4];
      #pragma unroll
      for (int i=0;i<2;i++)    paf[i]  = *(const f16x8*)(Pt  + (wave*32+i*16+fr)*136 + kp*32 + fk);
      #pragma unroll
      for (int jj=0;jj<4;jj++) pbf[jj] = *(const f16x8*)(Vtl + (jj*16+fr)*136 + kp*32 + fk);
      #pragma unroll
      for (int i=0;i<2;i++)
        #pragma unroll
        for (int jj=0;jj<4;jj++)
          oacc[i][jj] = __builtin_amdgcn_mfma_f32_16x16x32_f16(paf[i], pbf[jj], oacc[i][jj],0,0,0);
    }
  }

  float il[2][4];
  #pragma unroll
  for (int i=0;i<2;i++) for (int r=0;r<4;r++) il[i][r] = 1.0f/lrow[i][r];
  #pragma unroll
  for (int i=0;i<2;i++)
    #pragma unroll
    for (int jj=0;jj<4;jj++)
      #pragma unroll
      for (int r=0;r<4;r++){
        int row = m0 + wave*32 + i*16 + cr + r;
        Ob[((long)(b*NTOK + row))*DMODEL + h*HD + jj*16 + fr] = f2bf(oacc[i][jj][r]*il[i][r]);
      }
  if (fr == 0){
    #pragma unroll
    for (int i=0;i<2;i++)
      #pragma unroll
      for (int r=0;r<4;r++){
        int row = m0 + wave*32 + i*16 + cr + r;
        long off = ((long)(b*NHEADS+h))*NTOK + row;
        mbuf [off] = mrow[i][r];
        ilbuf[off] = il[i][r];
        entb [off] = Trow[i][r]*il[i][r] - logf(lrow[i][r]);  // = sum a*ln(a)
      }
  }
}

// ---- avg over heads from spilled P; folds the ^10 sinkhorn prep into epilogue. ----
__global__ __launch_bounds__(256) void attnB_kernel(
    const unsigned short* __restrict__ Pbig, const float* __restrict__ mscale,
    const float* __restrict__ mbuf, const float* __restrict__ ilbuf,
    float* __restrict__ avg, int h0, int gcnt, int first, int last)
{
  const int tid = threadIdx.x;
  const int j = blockIdx.x, mb = blockIdx.y, b = blockIdx.z;
  const int rsub = tid>>4, csub = (tid&15)*8;
  for (int p=0;p<8;p++){
    int row = mb*128 + p*16 + rsub;
    long obase = ((long)(b*NTOK + row))*NTOK + j*128 + csub;
    float acc[8];
    if (first){
      #pragma unroll
      for (int e=0;e<8;e++) acc[e]=0.f;
    } else {
      float4 a0 = *(const float4*)(avg+obase);
      float4 a1 = *(const float4*)(avg+obase+4);
      acc[0]=a0.x; acc[1]=a0.y; acc[2]=a0.z; acc[3]=a0.w;
      acc[4]=a1.x; acc[5]=a1.y; acc[6]=a1.z; acc[7]=a1.w;
    }
    for (int hh=0; hh<gcnt; hh++){
      int h = h0+hh;
      float mt = mscale[(((long)(b*NHEADS+h))*16 + j)*NTOK + row];
      long off = ((long)(b*NHEADS+h))*NTOK + row;
      float sc = expf(mt - mbuf[off]) * ilbuf[off];
      f16x8 pv = *(const f16x8*)(Pbig + (((long)(b*gcnt+hh)*NTOK + row))*NTOK + j*128 + csub);
      #pragma unroll
      for (int e=0;e<8;e++) acc[e] += (float)pv[e]*sc;
    }
    if (last){
      #pragma unroll
      for (int e=0;e<8;e++) acc[e] = expf(logf(acc[e]*0.0625f + EPSF)*10.0f);
    }
    float4 s0 = {acc[0],acc[1],acc[2],acc[3]};
    float4 s1 = {acc[4],acc[5],acc[6],acc[7]};
    *(float4*)(avg+obase)   = s0;
    *(float4*)(avg+obase+4) = s1;
  }
}

// ---- persistent sinkhorn: 10 iterations + argmax, one launch, 256 blocks ----
__global__ __launch_bounds__(256) void sink_kernel(
    const float* __restrict__ P, const float* __restrict__ PT,
    double* __restrict__ uv, const int* __restrict__ perm,
    float* __restrict__ dout_perm, int* __restrict__ bar)
{
  const int tid  = threadIdx.x;
  const int lane = tid & 63;
  const int wave = tid >> 6;
  const int row0 = blockIdx.x*16 + wave*4;    // 4 rows per wave (of 4096)
  const int b    = row0 >> 11;
  double* u = uv;
  double* v = uv + 4096;
  int tgt = 256;

  for (int it=0; it<10; it++){
    {   // u update: s_i = sum_j P[row][j] * v[b][j]
      const float* r0 = P + (long)row0*NTOK;
      const double* vb = v + (b<<11);
      double a0=0,a1=0,a2=0,a3=0;
      for (int k=0;k<32;k++){
        int jj = lane + (k<<6);
        double vv = vb[jj];
        a0 += (double)r0[jj       ]*vv;
        a1 += (double)r0[2048+jj  ]*vv;
        a2 += (double)r0[4096+jj  ]*vv;
        a3 += (double)r0[6144+jj  ]*vv;
      }
      a0=wred_sumd(a0); a1=wred_sumd(a1); a2=wred_sumd(a2); a3=wred_sumd(a3);
      if (lane==0){
        double s[4]={a0,a1,a2,a3};
        #pragma unroll
        for (int rr=0;rr<4;rr++){
          double ui = u[row0+rr];
          u[row0+rr] = ui/(ui*s[rr]+EPSD);
        }
      }
    }
    gbar(bar, tgt); tgt += 256;
    {   // v update: t_j = sum_i PT[rowT][i] * u[b][i]
      const float* r0 = PT + (long)row0*NTOK;
      const double* ub = u + (b<<11);
      double a0=0,a1=0,a2=0,a3=0;
      for (int k=0;k<32;k++){
        int jj = lane + (k<<6);
        double uu = ub[jj];
        a0 += (double)r0[jj       ]*uu;
        a1 += (double)r0[2048+jj  ]*uu;
        a2 += (double)r0[4096+jj  ]*uu;
        a3 += (double)r0[6144+jj  ]*uu;
      }
      a0=wred_sumd(a0); a1=wred_sumd(a1); a2=wred_sumd(a2); a3=wred_sumd(a3);
      if (lane==0){
        double t[4]={a0,a1,a2,a3};
        #pragma unroll
        for (int rr=0;rr<4;rr++){
          double vj = v[row0+rr];
          v[row0+rr] = vj/(vj*t[rr]+EPSD);
        }
      }
    }
    gbar(bar, tgt); tgt += 256;
  }

  // argmax_j P[row][j]*v[b][j], tie -> lowest j
  const double* vb = v + (b<<11);
  for (int rr=0;rr<4;rr++){
    int row = row0 + rr;
    const float* pr = P + (long)row*NTOK;
    double bv = -1.0; int bj = 0;
    for (int k=0;k<32;k++){
      int jj = lane + (k<<6);
      double val = (double)pr[jj]*vb[jj];
      if (val > bv){ bv = val; bj = jj; }     // jj ascending within thread
    }
    for (int o=1;o<64;o<<=1){
      double ov=__shfl_xor(bv,o); int oj=__shfl_xor(bj,o);
      if (ov>bv || (ov==bv && oj<bj)){ bv=ov; bj=oj; }
    }
    if (lane==0) dout_perm[row] = (float)perm[(b<<11) + bj];
  }
}

__global__ __launch_bounds__(256) void out_kernel(
    const unsigned short* __restrict__ Ob, const unsigned short* __restrict__ Wob,
    const float* __restrict__ bo, float* __restrict__ dout)
{
  __shared__ unsigned short lds[(128+128)*32];
  int m0 = blockIdx.x*128, n0 = blockIdx.y*128;
  f32x4 acc[4][4];
  f32x4 z = {0.f,0.f,0.f,0.f};
  for (int i=0;i<4;i++) for(int j=0;j<4;j++) acc[i][j] = z;
  gemm_bt_core<128,128>(Ob + (long)m0*DMODEL, DMODEL, Wob + (long)n0*DMODEL, DMODEL,
                        DMODEL, acc, lds, lds + 128*32);
  int lane = threadIdx.x & 63, wave = threadIdx.x >> 6;
  int wm = wave>>1, wn = wave&1;
  int cr = (lane>>4)<<2, cc = lane & 15;
  for (int i=0;i<4;i++) for(int j=0;j<4;j++) for(int r=0;r<4;r++){
    int row = m0 + wm*64 + i*16 + cr + r;
    int col = n0 + wn*64 + j*16 + cc;
    dout[(long)row*DMODEL + col] = acc[i][j][r] + bo[col];
  }
}

__global__ void cert_kernel(const float* __restrict__ cert,
    const float* __restrict__ ctemp, const float* __restrict__ entb,
    float* __restrict__ dout_cert)
{
  int idx = blockIdx.x*256+threadIdx.x;
  if (idx >= BATCH*NTOK) return;
  int b = idx >> 11, row = idx & 2047;
  float s = 0.f;
  #pragma unroll
  for (int h=0; h<NHEADS; h++) s += entb[((long)(b*NHEADS+h))*NTOK + row];
  float ent = -s * (1.0f/16.0f);
  float ct = ctemp[0];
  float arg = ct * (logf((float)NTOK) - ent);
  float upd = 1.0f/(1.0f+expf(-arg));
  dout_cert[idx] = fmaxf(cert[idx], upd);
}

extern "C" void kernel_launch(void* const* d_in, const int* in_sizes, int n_in,
                              void* d_out, int out_size, void* d_ws, size_t ws_size,
                              hipStream_t stream)
{
  const float* x    = (const float*)d_in[0];
  const float* cert = (const float*)d_in[1];
  const int*   perm = (const int*)d_in[2];
  const float* Wq   = (const float*)d_in[3];
  const float* bq   = (const float*)d_in[4];
  const float* Wk   = (const float*)d_in[5];
  const float* bk   = (const float*)d_in[6];
  const float* Wv   = (const float*)d_in[7];
  const float* bv   = (const float*)d_in[8];
  const float* Wo   = (const float*)d_in[9];
  const float* bo   = (const float*)d_in[10];
  const float* psc  = (const float*)d_in[11];
  const float* ctmp = (const float*)d_in[12];
  float* dout = (float*)d_out;

  // layout: doubles, ints, f32 arrays, bf16 region, Pbig
  double* uv   = (double*)d_ws;                         // 8192 (u, then v)
  int*   bar   = (int*)(uv + 8192);                     // 4 (padded to 16B)
  float* avg   = (float*)(bar + 4);                     // 8,388,608
  float* avgT  = avg   + 8388608;                       // 8,388,608
  float* mbuf  = avgT  + 8388608;                       // 65,536
  float* ilbuf = mbuf  + 65536;                         // 65,536
  float* entb  = ilbuf + 65536;                         // 65,536
  float* mscale= entb  + 65536;                         // 1,048,576
  unsigned short* xb  = (unsigned short*)(mscale + 1048576);  // 4,194,304
  unsigned short* Wqb = xb  + 4194304;
  unsigned short* Wkb = Wqb + 1048576;
  unsigned short* Wvb = Wkb + 1048576;
  unsigned short* Wob = Wvb + 1048576;
  unsigned short* Qb  = Wob + 1048576;                  // 4,194,304 each
  unsigned short* Kb  = Qb  + 4194304;
  unsigned short* Vb  = Kb  + 4194304;
  unsigned short* Vt  = Vb  + 4194304;
  unsigned short* Ob  = Vt  + 4194304;                  // 4,194,304
  unsigned short* Pbig= Ob  + 4194304;                  // G * 16,777,216 B

  const size_t fixedBytes = 8192*8 + 16
                          + (size_t)(8388608*2 + 65536*3 + 1048576)*4
                          + (size_t)29360128*2;         // ~130.9 MB
  int G = 16;
  while (G > 1 && fixedBytes + (size_t)G*16777216ull > ws_size) G >>= 1;

  f2b_kernel<<<dim3(16384),256,0,stream>>>(x,  xb,  4194304);
  f2b_kernel<<<dim3(4096), 256,0,stream>>>(Wq, Wqb, 1048576);
  f2b_kernel<<<dim3(4096), 256,0,stream>>>(Wk, Wkb, 1048576);
  f2b_kernel<<<dim3(4096), 256,0,stream>>>(Wv, Wvb, 1048576);
  f2b_kernel<<<dim3(4096), 256,0,stream>>>(Wo, Wob, 1048576);
  init_kernel<<<dim3(32),256,0,stream>>>(uv, bar);

  qkv_kernel<<<dim3(32,24),256,0,stream>>>(xb, Wqb,bq, Wkb,bk, Wvb,bv, Qb,Kb,Vb);
  vtrans_kernel<<<dim3(64,32,2), dim3(32,8),0,stream>>>(Vb, Vt);

  for (int h0=0; h0<NHEADS; h0+=G){
    attnA_kernel<<<dim3(16,G,2),256,0,stream>>>(Qb, Kb, Vt, perm, psc,
        Ob, mbuf, ilbuf, entb, mscale, Pbig, h0, G);
    attnB_kernel<<<dim3(16,16,2),256,0,stream>>>(Pbig, mscale, mbuf, ilbuf,
        avg, h0, G, (h0==0)?1:0, (h0+G>=NHEADS)?1:0);
  }

  ftrans_kernel<<<dim3(64,64,2), dim3(32,8),0,stream>>>(avg, avgT);
  sink_kernel<<<dim3(256),256,0,stream>>>(avg, avgT, uv, perm,
      dout + 4194304 + 4096, bar);

  out_kernel <<<dim3(32,8),256,0,stream>>>(Ob, Wob, bo, dout);
  cert_kernel<<<dim3(16), 256,0,stream>>>(cert, ctmp, entb, dout + 4194304);
}

// Round 7
// 1522.036 us; speedup vs baseline: 1.0549x; 1.0549x over previous
//
#include <hip/hip_runtime.h>
#include <cstdint>

#define NTOK 2048
#define DMODEL 1024
#define NHEADS 16
#define HD 64
#define BATCH 2
#define EPSF 1e-10f
#define EPSD 1e-10

typedef __attribute__((ext_vector_type(8))) short bf16x8;
typedef __attribute__((ext_vector_type(8))) _Float16 f16x8;
typedef __attribute__((ext_vector_type(4))) float f32x4;

__device__ __forceinline__ float bf2f(unsigned short u){
  union { unsigned int i; float f; } c; c.i = ((unsigned int)u) << 16; return c.f;
}
__device__ __forceinline__ unsigned short f2bf(float f){
  union { float f; unsigned int u; } c; c.f = f;
  unsigned int u = c.u;
  unsigned int r = (u + 0x7FFFu + ((u >> 16) & 1u)) >> 16;
  return (unsigned short)r;
}
__device__ __forceinline__ unsigned short f2h(float f){
  union { _Float16 h; unsigned short u; } c; c.h = (_Float16)f; return c.u;
}

__device__ __forceinline__ void async16(const unsigned short* g, unsigned short* lds_base){
  __builtin_amdgcn_global_load_lds((const __attribute__((address_space(1))) unsigned int*)g,
                                   (__attribute__((address_space(3))) unsigned int*)lds_base,
                                   16, 0, 0);
}

// C[m,n] = sum_k A[m,k] * B[n,k]  (both K-major bf16), 256 threads, waves 2x2.
template<int BM, int BN>
__device__ __forceinline__ void gemm_bt_core(
    const unsigned short* A, int lda,
    const unsigned short* B, int ldb,
    int K,
    f32x4 (&acc)[BM/32][BN/32],
    unsigned short* ldsA, unsigned short* ldsB)
{
  constexpr int TM = BM/32, TN = BN/32;
  const int tid  = threadIdx.x;
  const int lane = tid & 63;
  const int wave = tid >> 6;
  const int wm = wave >> 1, wn = wave & 1;
  const int fr = lane & 15;
  const int fk = (lane >> 4) << 3;
  const int sr = lane >> 2;
  const int sk = (lane & 3) << 3;

  for (int k0 = 0; k0 < K; k0 += 32){
    #pragma unroll
    for (int c = 0; c < BM/64; c++){
      int ch = c*4 + wave;
      async16(A + (long)(ch*16 + sr)*lda + (k0 + sk), ldsA + ch*512);
    }
    #pragma unroll
    for (int c = 0; c < BN/64; c++){
      int ch = c*4 + wave;
      async16(B + (long)(ch*16 + sr)*ldb + (k0 + sk), ldsB + ch*512);
    }
    __syncthreads();
    bf16x8 af[TM], bf[TN];
    #pragma unroll
    for (int i=0;i<TM;i++)
      af[i] = *(const bf16x8*)(ldsA + ((wm*TM*16) + i*16 + fr)*32 + fk);
    #pragma unroll
    for (int j=0;j<TN;j++)
      bf[j] = *(const bf16x8*)(ldsB + ((wn*TN*16) + j*16 + fr)*32 + fk);
    #pragma unroll
    for (int i=0;i<TM;i++)
      #pragma unroll
      for (int j=0;j<TN;j++)
        acc[i][j] = __builtin_amdgcn_mfma_f32_16x16x32_bf16(af[i], bf[j], acc[i][j], 0, 0, 0);
    __syncthreads();
  }
}

// grid-wide barrier (all 256 blocks resident: 1 block/CU by LDS)
__device__ __forceinline__ void gbar(int* bar, int target){
  __threadfence();
  __syncthreads();
  if (threadIdx.x == 0){
    atomicAdd(bar, 1);
    while (atomicAdd(bar, 0) < target) __builtin_amdgcn_s_sleep(2);
  }
  __syncthreads();
  __threadfence();
}

// ---------------- kernels ----------------

__global__ void f2b_kernel(const float* __restrict__ in, unsigned short* __restrict__ out, int n){
  int i = blockIdx.x*256 + threadIdx.x;
  if (i < n) out[i] = f2bf(in[i]);
}

// zero Sit/Tit (81920 doubles) + bar
__global__ void init_kernel(double* __restrict__ Sit, int* __restrict__ bar){
  int idx = blockIdx.x*256 + threadIdx.x;
  if (idx < 81920) Sit[idx] = 0.0;
  if (idx == 0) bar[0] = 0;
}

__global__ __launch_bounds__(256) void qkv_kernel(
    const unsigned short* __restrict__ xb,
    const unsigned short* __restrict__ Wqb, const float* __restrict__ bq,
    const unsigned short* __restrict__ Wkb, const float* __restrict__ bk,
    const unsigned short* __restrict__ Wvb, const float* __restrict__ bv,
    unsigned short* __restrict__ Qb, unsigned short* __restrict__ Kb,
    unsigned short* __restrict__ Vb)
{
  __shared__ unsigned short lds[(128+128)*32];
  int sel = blockIdx.y >> 3;
  int n0 = (blockIdx.y & 7) * 128;
  int m0 = blockIdx.x * 128;
  const unsigned short* W = sel==0 ? Wqb : (sel==1 ? Wkb : Wvb);
  const float* bias       = sel==0 ? bq  : (sel==1 ? bk  : bv);
  unsigned short* out     = sel==0 ? Qb  : (sel==1 ? Kb  : Vb);
  f32x4 acc[4][4];
  f32x4 z = {0.f,0.f,0.f,0.f};
  for (int i=0;i<4;i++) for(int j=0;j<4;j++) acc[i][j] = z;
  gemm_bt_core<128,128>(xb + (long)m0*DMODEL, DMODEL, W + (long)n0*DMODEL, DMODEL,
                        DMODEL, acc, lds, lds + 128*32);
  int lane = threadIdx.x & 63, wave = threadIdx.x >> 6;
  int wm = wave>>1, wn = wave&1;
  int cr = (lane>>4)<<2, cc = lane & 15;
  for (int i=0;i<4;i++) for(int j=0;j<4;j++) for(int r=0;r<4;r++){
    int row = m0 + wm*64 + i*16 + cr + r;
    int col = n0 + wn*64 + j*16 + cc;
    out[(long)row*DMODEL + col] = f2bf(acc[i][j][r] + bias[col]);
  }
}

__global__ void vtrans_kernel(const unsigned short* __restrict__ Vb,
                              unsigned short* __restrict__ Vt)
{
  __shared__ unsigned short t[32][33];
  int b = blockIdx.z, i0 = blockIdx.x*32, e0 = blockIdx.y*32;
  int tx = threadIdx.x, ty = threadIdx.y;
  for (int r=0;r<32;r+=8) t[ty+r][tx] = Vb[((long)b*NTOK + i0+ty+r)*DMODEL + e0+tx];
  __syncthreads();
  for (int r=0;r<32;r+=8) Vt[((long)b*DMODEL + e0+ty+r)*NTOK + i0+tx] = t[tx][ty+r];
}

// ---- single-pass flash attention per (b,h,row-block)  [round-4 verbatim] ----
__global__ __launch_bounds__(256,2) void attnA_kernel(
    const unsigned short* __restrict__ Qb, const unsigned short* __restrict__ Kb,
    const unsigned short* __restrict__ Vt, const int* __restrict__ perm,
    const float* __restrict__ psc,
    unsigned short* __restrict__ Ob, float* __restrict__ mbuf,
    float* __restrict__ ilbuf, float* __restrict__ entb,
    float* __restrict__ mscale, unsigned short* __restrict__ Pbig,
    int h0, int gcnt)
{
  __shared__ unsigned short Kt[2*128*32];   // bf16 [kc][row][32]
  __shared__ unsigned short Vtl[64*136];    // f16  [ocol][128+pad]
  __shared__ unsigned short Pt[128*136];    // f16  [row][128+pad]
  __shared__ unsigned short pbs[2048];

  const int tid  = threadIdx.x;
  const int lane = tid & 63;
  const int wave = tid >> 6;
  const int fr   = lane & 15;
  const int fkg  = lane >> 4;
  const int fk   = fkg << 3;
  const int cr   = fkg << 2;
  const int m0   = blockIdx.x * 128;
  const int hl   = blockIdx.y;
  const int h    = h0 + hl;
  const int b    = blockIdx.z;

  for (int i = tid; i < 2048; i += 256) pbs[i] = (unsigned short)perm[b*NTOK + i];

  bf16x8 qf[2][2];
  #pragma unroll
  for (int i=0;i<2;i++)
    #pragma unroll
    for (int kc=0;kc<2;kc++)
      qf[i][kc] = *(const bf16x8*)(Qb + ((long)(b*NTOK + m0 + wave*32 + i*16 + fr))*DMODEL + h*HD + kc*32 + fk);

  const float asc = fabsf(psc[h]);
  __syncthreads();

  float prow[2][4];
  #pragma unroll
  for (int i=0;i<2;i++)
    #pragma unroll
    for (int r=0;r<4;r++)
      prow[i][r] = (float)pbs[m0 + wave*32 + i*16 + cr + r];

  float mrow[2][4], lrow[2][4], Trow[2][4];
  #pragma unroll
  for (int i=0;i<2;i++) for(int r=0;r<4;r++){ mrow[i][r] = -1e30f; lrow[i][r] = 0.f; Trow[i][r] = 0.f; }
  f32x4 oacc[2][4];
  {
    f32x4 z = {0.f,0.f,0.f,0.f};
    for (int i=0;i<2;i++) for(int jj=0;jj<4;jj++) oacc[i][jj]=z;
  }

  for (int j=0;j<16;j++){
    __syncthreads();           // protect Kt/Vtl/Pt reuse across iterations
    #pragma unroll
    for (int c=0;c<4;c++){
      int q = wave*4 + c;
      int kc = q >> 3, rb = (q & 7) * 16;
      async16(Kb + ((long)(b*NTOK + j*128 + rb + (lane>>2)))*DMODEL + h*HD + kc*32 + ((lane&3)<<3),
              Kt + kc*4096 + rb*32);
    }
    {   // V tile: bf16 global -> f16 LDS
      int c = tid>>2, sg = tid&3;
      const unsigned short* vg = Vt + ((long)(b*DMODEL + h*HD + c))*NTOK + j*128 + sg*32;
      unsigned short* vl = Vtl + c*136 + sg*32;
      #pragma unroll
      for (int s2=0;s2<4;s2++){
        bf16x8 vv = *(const bf16x8*)(vg + s2*8);
        unsigned short tmp[8];
        #pragma unroll
        for (int e=0;e<8;e++) tmp[e] = f2h(bf2f(((unsigned short*)&vv)[e]));
        *(uint4*)(vl + s2*8) = *(uint4*)tmp;
      }
    }
    __syncthreads();

    f32x4 sacc[2][8];
    {
      f32x4 z = {0.f,0.f,0.f,0.f};
      for (int i=0;i<2;i++) for(int jj=0;jj<8;jj++) sacc[i][jj]=z;
    }
    #pragma unroll
    for (int kc=0;kc<2;kc++){
      bf16x8 bfr[8];
      #pragma unroll
      for (int jj=0;jj<8;jj++) bfr[jj] = *(const bf16x8*)(Kt + kc*4096 + (jj*16+fr)*32 + fk);
      #pragma unroll
      for (int i=0;i<2;i++)
        #pragma unroll
        for (int jj=0;jj<8;jj++)
          sacc[i][jj] = __builtin_amdgcn_mfma_f32_16x16x32_bf16(qf[i][kc], bfr[jj], sacc[i][jj],0,0,0);
    }

    float pcol[8];
    #pragma unroll
    for (int jj=0;jj<8;jj++) pcol[jj] = (float)pbs[j*128 + jj*16 + fr];

    #pragma unroll
    for (int i=0;i<2;i++)
      #pragma unroll
      for (int r=0;r<4;r++){
        float sv[8];
        float tm = -1e30f;
        #pragma unroll
        for (int jj=0;jj<8;jj++){
          sv[jj] = sacc[i][jj][r]*0.125f - fabsf(prow[i][r]-pcol[jj])*asc;
          tm = fmaxf(tm, sv[jj]);
        }
        #pragma unroll
        for (int o=1;o<16;o<<=1) tm = fmaxf(tm, __shfl_xor(tm,o));
        float nm = fmaxf(mrow[i][r], tm);
        float alpha = expf(mrow[i][r] - nm);
        float lres = lrow[i][r]*alpha;
        Trow[i][r] = Trow[i][r]*alpha + (mrow[i][r]-nm)*lres;
        #pragma unroll
        for (int jc=0;jc<4;jc++) oacc[i][jc][r] *= alpha;
        float ts=0.f, tT=0.f;
        int prowbase = (wave*32 + i*16 + cr + r)*136;
        #pragma unroll
        for (int jj=0;jj<8;jj++){
          float d = sv[jj]-nm;
          float ev = expf(d);
          ts += ev; tT += ev*d;
          Pt[prowbase + jj*16 + fr] = f2h(ev);
        }
        #pragma unroll
        for (int o=1;o<16;o<<=1){ ts += __shfl_xor(ts,o); tT += __shfl_xor(tT,o); }
        lrow[i][r] = lres + ts;
        Trow[i][r] += tT;
        mrow[i][r] = nm;
        if (fr==0)
          mscale[(((long)(b*NHEADS+h))*16 + j)*NTOK + m0 + wave*32 + i*16 + cr + r] = nm;
      }
    __syncthreads();
    {   // coalesced P tile spill (f16)
      const uint4* src = (const uint4*)(Pt + (tid>>1)*136 + (tid&1)*64);
      uint4* dst = (uint4*)(Pbig + (((long)(b*gcnt + hl)*NTOK + m0 + (tid>>1)))*NTOK + j*128 + (tid&1)*64);
      #pragma unroll
      for (int q=0;q<8;q++) dst[q] = src[q];
    }
    #pragma unroll
    for (int kp=0;kp<4;kp++){
      f16x8 paf[2], pbf[4];
      #pragma unroll
      for (int i=0;i<2;i++)    paf[i]  = *(const f16x8*)(Pt  + (wave*32+i*16+fr)*136 + kp*32 + fk);
      #pragma unroll
      for (int jj=0;jj<4;jj++) pbf[jj] = *(const f16x8*)(Vtl + (jj*16+fr)*136 + kp*32 + fk);
      #pragma unroll
      for (int i=0;i<2;i++)
        #pragma unroll
        for (int jj=0;jj<4;jj++)
          oacc[i][jj] = __builtin_amdgcn_mfma_f32_16x16x32_f16(paf[i], pbf[jj], oacc[i][jj],0,0,0);
    }
  }

  float il[2][4];
  #pragma unroll
  for (int i=0;i<2;i++) for (int r=0;r<4;r++) il[i][r] = 1.0f/lrow[i][r];
  #pragma unroll
  for (int i=0;i<2;i++)
    #pragma unroll
    for (int jj=0;jj<4;jj++)
      #pragma unroll
      for (int r=0;r<4;r++){
        int row = m0 + wave*32 + i*16 + cr + r;
        Ob[((long)(b*NTOK + row))*DMODEL + h*HD + jj*16 + fr] = f2bf(oacc[i][jj][r]*il[i][r]);
      }
  if (fr == 0){
    #pragma unroll
    for (int i=0;i<2;i++)
      #pragma unroll
      for (int r=0;r<4;r++){
        int row = m0 + wave*32 + i*16 + cr + r;
        long off = ((long)(b*NHEADS+h))*NTOK + row;
        mbuf [off] = mrow[i][r];
        ilbuf[off] = il[i][r];
        entb [off] = Trow[i][r]*il[i][r] - logf(lrow[i][r]);  // = sum a*ln(a)
      }
  }
}

// ---- avg over heads from spilled P; folds the ^10 sinkhorn prep into epilogue. ----
__global__ __launch_bounds__(256) void attnB_kernel(
    const unsigned short* __restrict__ Pbig, const float* __restrict__ mscale,
    const float* __restrict__ mbuf, const float* __restrict__ ilbuf,
    float* __restrict__ avg, int h0, int gcnt, int first, int last)
{
  const int tid = threadIdx.x;
  const int j = blockIdx.x, mb = blockIdx.y, b = blockIdx.z;
  const int rsub = tid>>4, csub = (tid&15)*8;
  for (int p=0;p<8;p++){
    int row = mb*128 + p*16 + rsub;
    long obase = ((long)(b*NTOK + row))*NTOK + j*128 + csub;
    float acc[8];
    if (first){
      #pragma unroll
      for (int e=0;e<8;e++) acc[e]=0.f;
    } else {
      float4 a0 = *(const float4*)(avg+obase);
      float4 a1 = *(const float4*)(avg+obase+4);
      acc[0]=a0.x; acc[1]=a0.y; acc[2]=a0.z; acc[3]=a0.w;
      acc[4]=a1.x; acc[5]=a1.y; acc[6]=a1.z; acc[7]=a1.w;
    }
    for (int hh=0; hh<gcnt; hh++){
      int h = h0+hh;
      float mt = mscale[(((long)(b*NHEADS+h))*16 + j)*NTOK + row];
      long off = ((long)(b*NHEADS+h))*NTOK + row;
      float sc = expf(mt - mbuf[off]) * ilbuf[off];
      f16x8 pv = *(const f16x8*)(Pbig + (((long)(b*gcnt+hh)*NTOK + row))*NTOK + j*128 + csub);
      #pragma unroll
      for (int e=0;e<8;e++) acc[e] += (float)pv[e]*sc;
    }
    if (last){
      #pragma unroll
      for (int e=0;e<8;e++) acc[e] = expf(logf(acc[e]*0.0625f + EPSF)*10.0f);
    }
    float4 s0 = {acc[0],acc[1],acc[2],acc[3]};
    float4 s1 = {acc[4],acc[5],acc[6],acc[7]};
    *(float4*)(avg+obase)   = s0;
    *(float4*)(avg+obase+4) = s1;
  }
}

// ---- persistent LDS-resident sinkhorn + argmax. 256 blocks, 1 block/CU.
// Block (b, rb, cb) owns tile rows rb*128..+127, cols cb*256..+255 of P (f32, LDS).
// u/v replicated per band in LDS (f64); S/T per-iteration global accumulators. ----
__global__ __launch_bounds__(256,1) void sink_persist(
    const float* __restrict__ avg, double* __restrict__ Sit, double* __restrict__ Tit,
    double* __restrict__ Candv, int* __restrict__ Candj,
    const int* __restrict__ perm, float* __restrict__ dout_perm, int* __restrict__ bar)
{
  __shared__ float tile[128][257];    // +1 pad: row-sum reads conflict-free
  __shared__ double vlds[256];
  __shared__ double ulds[128];
  const int tid = threadIdx.x;
  const int g   = blockIdx.x;
  const int b   = g >> 7;
  const int rb  = (g >> 3) & 15;
  const int cb  = g & 7;
  const int row0 = b*2048 + rb*128;    // global row index space (0..4095)
  const int col0 = cb*256;             // col within batch

  for (int idx = tid; idx < 32768; idx += 256){
    int r = idx >> 8, c = idx & 255;
    tile[r][c] = avg[((long)(row0 + r))*2048 + col0 + c];
  }
  if (tid < 128) ulds[tid] = 1.0;
  vlds[tid] = 1.0;
  __syncthreads();

  const int hrow = tid >> 1;
  const int half = tid & 1;
  int tgt = 256;
  for (int it=0; it<10; it++){
    {   // row sums: S_i += sum_j P_ij v_j  (this block's col range)
      double s = 0.0;
      #pragma unroll 4
      for (int k=0;k<128;k++)
        s += (double)tile[hrow][half*128+k] * vlds[half*128+k];
      s += __shfl_xor(s, 1);
      if (half==0) atomicAdd(&Sit[(long)it*4096 + row0 + hrow], s);
    }
    gbar(bar, tgt); tgt += 256;
    if (tid < 128){    // u update (replicated across the 8 col-band blocks)
      double S = Sit[(long)it*4096 + row0 + tid];
      double uo = ulds[tid];
      ulds[tid] = uo/(uo*S + EPSD);
    }
    __syncthreads();
    {   // col sums: T_j += sum_i P_ij u_i  (this block's row range)
      double t = 0.0;
      #pragma unroll 4
      for (int r=0;r<128;r++)
        t += (double)tile[r][tid] * ulds[r];
      atomicAdd(&Tit[(long)it*4096 + b*2048 + col0 + tid], t);
    }
    gbar(bar, tgt); tgt += 256;
    {   // v update (replicated across the 16 row-band blocks)
      double T = Tit[(long)it*4096 + b*2048 + col0 + tid];
      double vo = vlds[tid];
      vlds[tid] = vo/(vo*T + EPSD);
    }
    __syncthreads();
  }

  {   // per-tile argmax of P_ij * v_j (u_i>0 constant per row -> equivalent)
    double bv = -1.0; int bj = col0;
    for (int k=0;k<128;k++){
      int c = half*128 + k;
      double val = (double)tile[hrow][c] * vlds[c];
      if (val > bv){ bv = val; bj = col0 + c; }   // first-max kept (k ascending)
    }
    double ov = __shfl_xor(bv,1); int oj = __shfl_xor(bj,1);
    if (ov > bv || (ov==bv && oj < bj)){ bv = ov; bj = oj; }
    if (half==0){
      Candv[(long)(row0 + hrow)*8 + cb] = bv;
      Candj[(long)(row0 + hrow)*8 + cb] = bj;
    }
  }
  gbar(bar, tgt); tgt += 256;
  if (g < 16){   // final 8-way reduce, row = g*256 + tid
    int row = g*256 + tid;
    double bv = -1.0; int bj = 0;
    #pragma unroll
    for (int c=0;c<8;c++){
      double v2 = Candv[(long)row*8 + c]; int j2 = Candj[(long)row*8 + c];
      if (v2 > bv || (v2==bv && j2 < bj)){ bv=v2; bj=j2; }
    }
    dout_perm[row] = (float)perm[(row>>11)*2048 + bj];
  }
}

__global__ __launch_bounds__(256) void out_kernel(
    const unsigned short* __restrict__ Ob, const unsigned short* __restrict__ Wob,
    const float* __restrict__ bo, float* __restrict__ dout)
{
  __shared__ unsigned short lds[(128+128)*32];
  int m0 = blockIdx.x*128, n0 = blockIdx.y*128;
  f32x4 acc[4][4];
  f32x4 z = {0.f,0.f,0.f,0.f};
  for (int i=0;i<4;i++) for(int j=0;j<4;j++) acc[i][j] = z;
  gemm_bt_core<128,128>(Ob + (long)m0*DMODEL, DMODEL, Wob + (long)n0*DMODEL, DMODEL,
                        DMODEL, acc, lds, lds + 128*32);
  int lane = threadIdx.x & 63, wave = threadIdx.x >> 6;
  int wm = wave>>1, wn = wave&1;
  int cr = (lane>>4)<<2, cc = lane & 15;
  for (int i=0;i<4;i++) for(int j=0;j<4;j++) for(int r=0;r<4;r++){
    int row = m0 + wm*64 + i*16 + cr + r;
    int col = n0 + wn*64 + j*16 + cc;
    dout[(long)row*DMODEL + col] = acc[i][j][r] + bo[col];
  }
}

__global__ void cert_kernel(const float* __restrict__ cert,
    const float* __restrict__ ctemp, const float* __restrict__ entb,
    float* __restrict__ dout_cert)
{
  int idx = blockIdx.x*256+threadIdx.x;
  if (idx >= BATCH*NTOK) return;
  int b = idx >> 11, row = idx & 2047;
  float s = 0.f;
  #pragma unroll
  for (int h=0; h<NHEADS; h++) s += entb[((long)(b*NHEADS+h))*NTOK + row];
  float ent = -s * (1.0f/16.0f);
  float ct = ctemp[0];
  float arg = ct * (logf((float)NTOK) - ent);
  float upd = 1.0f/(1.0f+expf(-arg));
  dout_cert[idx] = fmaxf(cert[idx], upd);
}

extern "C" void kernel_launch(void* const* d_in, const int* in_sizes, int n_in,
                              void* d_out, int out_size, void* d_ws, size_t ws_size,
                              hipStream_t stream)
{
  const float* x    = (const float*)d_in[0];
  const float* cert = (const float*)d_in[1];
  const int*   perm = (const int*)d_in[2];
  const float* Wq   = (const float*)d_in[3];
  const float* bq   = (const float*)d_in[4];
  const float* Wk   = (const float*)d_in[5];
  const float* bk   = (const float*)d_in[6];
  const float* Wv   = (const float*)d_in[7];
  const float* bv   = (const float*)d_in[8];
  const float* Wo   = (const float*)d_in[9];
  const float* bo   = (const float*)d_in[10];
  const float* psc  = (const float*)d_in[11];
  const float* ctmp = (const float*)d_in[12];
  float* dout = (float*)d_out;

  // layout: f64 accumulators, candidates, bar, f32 arrays, bf16 region, Pbig
  double* Sit  = (double*)d_ws;                         // 40960 (10 x 4096)
  double* Tit  = Sit + 40960;                           // 40960
  double* Candv= Tit + 40960;                           // 32768 (4096 x 8)
  int*   Candj = (int*)(Candv + 32768);                 // 32768
  int*   bar   = Candj + 32768;                         // 4 (pad to 16B)
  float* avg   = (float*)(bar + 4);                     // 8,388,608
  float* mbuf  = avg   + 8388608;                       // 65,536
  float* ilbuf = mbuf  + 65536;                         // 65,536
  float* entb  = ilbuf + 65536;                         // 65,536
  float* mscale= entb  + 65536;                         // 1,048,576
  unsigned short* xb  = (unsigned short*)(mscale + 1048576);  // 4,194,304
  unsigned short* Wqb = xb  + 4194304;
  unsigned short* Wkb = Wqb + 1048576;
  unsigned short* Wvb = Wkb + 1048576;
  unsigned short* Wob = Wvb + 1048576;
  unsigned short* Qb  = Wob + 1048576;                  // 4,194,304 each
  unsigned short* Kb  = Qb  + 4194304;
  unsigned short* Vb  = Kb  + 4194304;
  unsigned short* Vt  = Vb  + 4194304;
  unsigned short* Ob  = Vt  + 4194304;                  // 4,194,304
  unsigned short* Pbig= Ob  + 4194304;                  // G * 16,777,216 B

  const size_t fixedBytes = (size_t)(40960*2 + 32768)*8 + 32768*4 + 16
                          + (size_t)(8388608 + 65536*3 + 1048576)*4
                          + (size_t)29360128*2;         // ~98.3 MB
  int G = 16;
  while (G > 1 && fixedBytes + (size_t)G*16777216ull > ws_size) G >>= 1;

  f2b_kernel<<<dim3(16384),256,0,stream>>>(x,  xb,  4194304);
  f2b_kernel<<<dim3(4096), 256,0,stream>>>(Wq, Wqb, 1048576);
  f2b_kernel<<<dim3(4096), 256,0,stream>>>(Wk, Wkb, 1048576);
  f2b_kernel<<<dim3(4096), 256,0,stream>>>(Wv, Wvb, 1048576);
  f2b_kernel<<<dim3(4096), 256,0,stream>>>(Wo, Wob, 1048576);
  init_kernel<<<dim3(320),256,0,stream>>>(Sit, bar);

  qkv_kernel<<<dim3(32,24),256,0,stream>>>(xb, Wqb,bq, Wkb,bk, Wvb,bv, Qb,Kb,Vb);
  vtrans_kernel<<<dim3(64,32,2), dim3(32,8),0,stream>>>(Vb, Vt);

  for (int h0=0; h0<NHEADS; h0+=G){
    attnA_kernel<<<dim3(16,G,2),256,0,stream>>>(Qb, Kb, Vt, perm, psc,
        Ob, mbuf, ilbuf, entb, mscale, Pbig, h0, G);
    attnB_kernel<<<dim3(16,16,2),256,0,stream>>>(Pbig, mscale, mbuf, ilbuf,
        avg, h0, G, (h0==0)?1:0, (h0+G>=NHEADS)?1:0);
  }

  sink_persist<<<dim3(256),256,0,stream>>>(avg, Sit, Tit, Candv, Candj,
      perm, dout + 4194304 + 4096, bar);

  out_kernel <<<dim3(32,8),256,0,stream>>>(Ob, Wob, bo, dout);
  cert_kernel<<<dim3(16), 256,0,stream>>>(cert, ctmp, entb, dout + 4194304);
}

// Round 8
// 637.981 us; speedup vs baseline: 2.5168x; 2.3857x over previous
//
#include <hip/hip_runtime.h>
#include <cstdint>

#define NTOK 2048
#define DMODEL 1024
#define NHEADS 16
#define HD 64
#define BATCH 2
#define EPSF 1e-10f
#define EPSD 1e-10

typedef __attribute__((ext_vector_type(8))) short bf16x8;
typedef __attribute__((ext_vector_type(8))) _Float16 f16x8;
typedef __attribute__((ext_vector_type(4))) float f32x4;

__device__ __forceinline__ float bf2f(unsigned short u){
  union { unsigned int i; float f; } c; c.i = ((unsigned int)u) << 16; return c.f;
}
__device__ __forceinline__ unsigned short f2bf(float f){
  union { float f; unsigned int u; } c; c.f = f;
  unsigned int u = c.u;
  unsigned int r = (u + 0x7FFFu + ((u >> 16) & 1u)) >> 16;
  return (unsigned short)r;
}
__device__ __forceinline__ unsigned short f2h(float f){
  union { _Float16 h; unsigned short u; } c; c.h = (_Float16)f; return c.u;
}

__device__ __forceinline__ void async16(const unsigned short* g, unsigned short* lds_base){
  __builtin_amdgcn_global_load_lds((const __attribute__((address_space(1))) unsigned int*)g,
                                   (__attribute__((address_space(3))) unsigned int*)lds_base,
                                   16, 0, 0);
}

// C[m,n] = sum_k A[m,k] * B[n,k]  (both K-major bf16), 256 threads, waves 2x2.
template<int BM, int BN>
__device__ __forceinline__ void gemm_bt_core(
    const unsigned short* A, int lda,
    const unsigned short* B, int ldb,
    int K,
    f32x4 (&acc)[BM/32][BN/32],
    unsigned short* ldsA, unsigned short* ldsB)
{
  constexpr int TM = BM/32, TN = BN/32;
  const int tid  = threadIdx.x;
  const int lane = tid & 63;
  const int wave = tid >> 6;
  const int wm = wave >> 1, wn = wave & 1;
  const int fr = lane & 15;
  const int fk = (lane >> 4) << 3;
  const int sr = lane >> 2;
  const int sk = (lane & 3) << 3;

  for (int k0 = 0; k0 < K; k0 += 32){
    #pragma unroll
    for (int c = 0; c < BM/64; c++){
      int ch = c*4 + wave;
      async16(A + (long)(ch*16 + sr)*lda + (k0 + sk), ldsA + ch*512);
    }
    #pragma unroll
    for (int c = 0; c < BN/64; c++){
      int ch = c*4 + wave;
      async16(B + (long)(ch*16 + sr)*ldb + (k0 + sk), ldsB + ch*512);
    }
    __syncthreads();
    bf16x8 af[TM], bf[TN];
    #pragma unroll
    for (int i=0;i<TM;i++)
      af[i] = *(const bf16x8*)(ldsA + ((wm*TM*16) + i*16 + fr)*32 + fk);
    #pragma unroll
    for (int j=0;j<TN;j++)
      bf[j] = *(const bf16x8*)(ldsB + ((wn*TN*16) + j*16 + fr)*32 + fk);
    #pragma unroll
    for (int i=0;i<TM;i++)
      #pragma unroll
      for (int j=0;j<TN;j++)
        acc[i][j] = __builtin_amdgcn_mfma_f32_16x16x32_bf16(af[i], bf[j], acc[i][j], 0, 0, 0);
    __syncthreads();
  }
}

__device__ __forceinline__ double wred_sumd(double x){
  for(int o=32;o;o>>=1) x+=__shfl_xor(x,o); return x;
}

// ---------------- kernels ----------------

// one conversion kernel for all five f32->bf16 regions (dst contiguous: x,Wq,Wk,Wv,Wo)
__global__ void f2b_multi(const float* __restrict__ x,
    const float* __restrict__ wq, const float* __restrict__ wk,
    const float* __restrict__ wv, const float* __restrict__ wo,
    unsigned short* __restrict__ out)
{
  int i = blockIdx.x*256 + threadIdx.x;   // grid covers 8,388,608
  float s;
  if (i < 4194304) s = x[i];
  else {
    int d = i - 4194304;
    int r = d >> 20, off = d & 1048575;
    s = (r==0 ? wq : (r==1 ? wk : (r==2 ? wv : wo)))[off];
  }
  out[i] = f2bf(s);
}

__global__ void init_kernel(double* __restrict__ uv){
  int idx = blockIdx.x*256 + threadIdx.x;
  if (idx < 8192) uv[idx] = 1.0;     // u, v
}

__global__ __launch_bounds__(256) void qkv_kernel(
    const unsigned short* __restrict__ xb,
    const unsigned short* __restrict__ Wqb, const float* __restrict__ bq,
    const unsigned short* __restrict__ Wkb, const float* __restrict__ bk,
    const unsigned short* __restrict__ Wvb, const float* __restrict__ bv,
    unsigned short* __restrict__ Qb, unsigned short* __restrict__ Kb,
    unsigned short* __restrict__ Vb)
{
  __shared__ unsigned short lds[(128+128)*32];
  int sel = blockIdx.y >> 3;
  int n0 = (blockIdx.y & 7) * 128;
  int m0 = blockIdx.x * 128;
  const unsigned short* W = sel==0 ? Wqb : (sel==1 ? Wkb : Wvb);
  const float* bias       = sel==0 ? bq  : (sel==1 ? bk  : bv);
  unsigned short* out     = sel==0 ? Qb  : (sel==1 ? Kb  : Vb);
  f32x4 acc[4][4];
  f32x4 z = {0.f,0.f,0.f,0.f};
  for (int i=0;i<4;i++) for(int j=0;j<4;j++) acc[i][j] = z;
  gemm_bt_core<128,128>(xb + (long)m0*DMODEL, DMODEL, W + (long)n0*DMODEL, DMODEL,
                        DMODEL, acc, lds, lds + 128*32);
  int lane = threadIdx.x & 63, wave = threadIdx.x >> 6;
  int wm = wave>>1, wn = wave&1;
  int cr = (lane>>4)<<2, cc = lane & 15;
  for (int i=0;i<4;i++) for(int j=0;j<4;j++) for(int r=0;r<4;r++){
    int row = m0 + wm*64 + i*16 + cr + r;
    int col = n0 + wn*64 + j*16 + cc;
    out[(long)row*DMODEL + col] = f2bf(acc[i][j][r] + bias[col]);
  }
}

__global__ void vtrans_kernel(const unsigned short* __restrict__ Vb,
                              unsigned short* __restrict__ Vt)
{
  __shared__ unsigned short t[32][33];
  int b = blockIdx.z, i0 = blockIdx.x*32, e0 = blockIdx.y*32;
  int tx = threadIdx.x, ty = threadIdx.y;
  for (int r=0;r<32;r+=8) t[ty+r][tx] = Vb[((long)b*NTOK + i0+ty+r)*DMODEL + e0+tx];
  __syncthreads();
  for (int r=0;r<32;r+=8) Vt[((long)b*DMODEL + e0+ty+r)*NTOK + i0+tx] = t[tx][ty+r];
}

// f32 per-batch transpose (for sinkhorn column pass)
__global__ void ftrans_kernel(const float* __restrict__ in, float* __restrict__ out){
  __shared__ float t[32][33];
  int b = blockIdx.z, i0 = blockIdx.x*32, j0 = blockIdx.y*32;
  int tx = threadIdx.x, ty = threadIdx.y;
  for (int r=0;r<32;r+=8) t[ty+r][tx] = in[((long)(b*NTOK + i0+ty+r))*NTOK + j0+tx];
  __syncthreads();
  for (int r=0;r<32;r+=8) out[((long)(b*NTOK + j0+ty+r))*NTOK + i0+tx] = t[tx][ty+r];
}

// ---- single-pass flash attention per (b,h,row-block). Round-4 structure
// (same 3 barriers/iter, same LDS), but 512 threads = 8 waves (16 rows each)
// for 16 waves/CU occupancy. ----
__global__ __launch_bounds__(512,4) void attnA_kernel(
    const unsigned short* __restrict__ Qb, const unsigned short* __restrict__ Kb,
    const unsigned short* __restrict__ Vt, const int* __restrict__ perm,
    const float* __restrict__ psc,
    unsigned short* __restrict__ Ob, float* __restrict__ mbuf,
    float* __restrict__ ilbuf, float* __restrict__ entb,
    float* __restrict__ mscale, unsigned short* __restrict__ Pbig,
    int h0, int gcnt)
{
  __shared__ unsigned short Kt[2*128*32];   // bf16 [kc][col][32]
  __shared__ unsigned short Vtl[64*136];    // f16  [ocol][128+pad]
  __shared__ unsigned short Pt[128*136];    // f16  [row][128+pad]
  __shared__ unsigned short pbs[2048];

  const int tid  = threadIdx.x;
  const int lane = tid & 63;
  const int wave = tid >> 6;              // 0..7, 16 rows each
  const int fr   = lane & 15;
  const int fkg  = lane >> 4;
  const int fk   = fkg << 3;
  const int cr   = fkg << 2;
  const int rw   = wave << 4;             // row base within 128-tile
  const int m0   = blockIdx.x * 128;
  const int hl   = blockIdx.y;
  const int h    = h0 + hl;
  const int b    = blockIdx.z;

  for (int i = tid; i < 2048; i += 512) pbs[i] = (unsigned short)perm[b*NTOK + i];

  bf16x8 qf[2];
  #pragma unroll
  for (int kc=0;kc<2;kc++)
    qf[kc] = *(const bf16x8*)(Qb + ((long)(b*NTOK + m0 + rw + fr))*DMODEL + h*HD + kc*32 + fk);

  const float asc = fabsf(psc[h]);
  __syncthreads();

  float prow[4];
  #pragma unroll
  for (int r=0;r<4;r++) prow[r] = (float)pbs[m0 + rw + cr + r];

  float mrow[4], lrow[4], Trow[4];
  #pragma unroll
  for (int r=0;r<4;r++){ mrow[r] = -1e30f; lrow[r] = 0.f; Trow[r] = 0.f; }
  f32x4 oacc[4];
  {
    f32x4 z = {0.f,0.f,0.f,0.f};
    for (int jj=0;jj<4;jj++) oacc[jj]=z;
  }

  for (int j=0;j<16;j++){
    __syncthreads();           // protect Kt/Vtl/Pt reuse across iterations
    #pragma unroll
    for (int c=0;c<2;c++){     // K tile: 16 chunks of (16 cols x 32 k)
      int q = c*8 + wave;
      int kc = q >> 3, rb = (q & 7) * 16;
      async16(Kb + ((long)(b*NTOK + j*128 + rb + (lane>>2)))*DMODEL + h*HD + kc*32 + ((lane&3)<<3),
              Kt + kc*4096 + rb*32);
    }
    {   // V tile: bf16 global -> f16 LDS (512 threads: 64 cols x 8 segs of 16)
      int c = tid>>3, sg = tid&7;
      const unsigned short* vg = Vt + ((long)(b*DMODEL + h*HD + c))*NTOK + j*128 + sg*16;
      unsigned short* vl = Vtl + c*136 + sg*16;
      #pragma unroll
      for (int s2=0;s2<2;s2++){
        bf16x8 vv = *(const bf16x8*)(vg + s2*8);
        unsigned short tmp[8];
        #pragma unroll
        for (int e=0;e<8;e++) tmp[e] = f2h(bf2f(((unsigned short*)&vv)[e]));
        *(uint4*)(vl + s2*8) = *(uint4*)tmp;
      }
    }
    __syncthreads();

    f32x4 sacc[8];
    {
      f32x4 z = {0.f,0.f,0.f,0.f};
      for (int jj=0;jj<8;jj++) sacc[jj]=z;
    }
    #pragma unroll
    for (int kc=0;kc<2;kc++){
      bf16x8 bfr[8];
      #pragma unroll
      for (int jj=0;jj<8;jj++) bfr[jj] = *(const bf16x8*)(Kt + kc*4096 + (jj*16+fr)*32 + fk);
      #pragma unroll
      for (int jj=0;jj<8;jj++)
        sacc[jj] = __builtin_amdgcn_mfma_f32_16x16x32_bf16(qf[kc], bfr[jj], sacc[jj],0,0,0);
    }

    float pcol[8];
    #pragma unroll
    for (int jj=0;jj<8;jj++) pcol[jj] = (float)pbs[j*128 + jj*16 + fr];

    #pragma unroll
    for (int r=0;r<4;r++){
      float sv[8];
      float tm = -1e30f;
      #pragma unroll
      for (int jj=0;jj<8;jj++){
        sv[jj] = sacc[jj][r]*0.125f - fabsf(prow[r]-pcol[jj])*asc;
        tm = fmaxf(tm, sv[jj]);
      }
      #pragma unroll
      for (int o=1;o<16;o<<=1) tm = fmaxf(tm, __shfl_xor(tm,o));
      float nm = fmaxf(mrow[r], tm);
      float alpha = expf(mrow[r] - nm);
      float lres = lrow[r]*alpha;
      Trow[r] = Trow[r]*alpha + (mrow[r]-nm)*lres;
      #pragma unroll
      for (int jc=0;jc<4;jc++) oacc[jc][r] *= alpha;
      float ts=0.f, tT=0.f;
      int prowbase = (rw + cr + r)*136;
      #pragma unroll
      for (int jj=0;jj<8;jj++){
        float d = sv[jj]-nm;
        float ev = expf(d);
        ts += ev; tT += ev*d;
        Pt[prowbase + jj*16 + fr] = f2h(ev);
      }
      #pragma unroll
      for (int o=1;o<16;o<<=1){ ts += __shfl_xor(ts,o); tT += __shfl_xor(tT,o); }
      lrow[r] = lres + ts;
      Trow[r] += tT;
      mrow[r] = nm;
      if (fr==0)
        mscale[(((long)(b*NHEADS+h))*16 + j)*NTOK + m0 + rw + cr + r] = nm;
    }
    __syncthreads();
    {   // coalesced P tile spill (f16): 512 threads x 64B
      const uint4* src = (const uint4*)(Pt + (tid>>2)*136 + (tid&3)*32);
      uint4* dst = (uint4*)(Pbig + (((long)(b*gcnt + hl)*NTOK + m0 + (tid>>2)))*NTOK + j*128 + (tid&3)*32);
      #pragma unroll
      for (int q=0;q<4;q++) dst[q] = src[q];
    }
    #pragma unroll
    for (int kp=0;kp<4;kp++){
      f16x8 paf, pbf[4];
      paf = *(const f16x8*)(Pt + (rw+fr)*136 + kp*32 + fk);
      #pragma unroll
      for (int jj=0;jj<4;jj++) pbf[jj] = *(const f16x8*)(Vtl + (jj*16+fr)*136 + kp*32 + fk);
      #pragma unroll
      for (int jj=0;jj<4;jj++)
        oacc[jj] = __builtin_amdgcn_mfma_f32_16x16x32_f16(paf, pbf[jj], oacc[jj],0,0,0);
    }
  }

  float il[4];
  #pragma unroll
  for (int r=0;r<4;r++) il[r] = 1.0f/lrow[r];
  #pragma unroll
  for (int jj=0;jj<4;jj++)
    #pragma unroll
    for (int r=0;r<4;r++){
      int row = m0 + rw + cr + r;
      Ob[((long)(b*NTOK + row))*DMODEL + h*HD + jj*16 + fr] = f2bf(oacc[jj][r]*il[r]);
    }
  if (fr == 0){
    #pragma unroll
    for (int r=0;r<4;r++){
      int row = m0 + rw + cr + r;
      long off = ((long)(b*NHEADS+h))*NTOK + row;
      mbuf [off] = mrow[r];
      ilbuf[off] = il[r];
      entb [off] = Trow[r]*il[r] - logf(lrow[r]);  // = sum a*ln(a)
    }
  }
}

// ---- avg over heads from spilled P; folds the ^10 sinkhorn prep into epilogue. ----
__global__ __launch_bounds__(256) void attnB_kernel(
    const unsigned short* __restrict__ Pbig, const float* __restrict__ mscale,
    const float* __restrict__ mbuf, const float* __restrict__ ilbuf,
    float* __restrict__ avg, int h0, int gcnt, int first, int last)
{
  const int tid = threadIdx.x;
  const int j = blockIdx.x, mb = blockIdx.y, b = blockIdx.z;
  const int rsub = tid>>4, csub = (tid&15)*8;
  for (int p=0;p<8;p++){
    int row = mb*128 + p*16 + rsub;
    long obase = ((long)(b*NTOK + row))*NTOK + j*128 + csub;
    float acc[8];
    if (first){
      #pragma unroll
      for (int e=0;e<8;e++) acc[e]=0.f;
    } else {
      float4 a0 = *(const float4*)(avg+obase);
      float4 a1 = *(const float4*)(avg+obase+4);
      acc[0]=a0.x; acc[1]=a0.y; acc[2]=a0.z; acc[3]=a0.w;
      acc[4]=a1.x; acc[5]=a1.y; acc[6]=a1.z; acc[7]=a1.w;
    }
    for (int hh=0; hh<gcnt; hh++){
      int h = h0+hh;
      float mt = mscale[(((long)(b*NHEADS+h))*16 + j)*NTOK + row];
      long off = ((long)(b*NHEADS+h))*NTOK + row;
      float sc = expf(mt - mbuf[off]) * ilbuf[off];
      f16x8 pv = *(const f16x8*)(Pbig + (((long)(b*gcnt+hh)*NTOK + row))*NTOK + j*128 + csub);
      #pragma unroll
      for (int e=0;e<8;e++) acc[e] += (float)pv[e]*sc;
    }
    if (last){
      #pragma unroll
      for (int e=0;e<8;e++) acc[e] = expf(logf(acc[e]*0.0625f + EPSF)*10.0f);
    }
    float4 s0 = {acc[0],acc[1],acc[2],acc[3]};
    float4 s1 = {acc[4],acc[5],acc[6],acc[7]};
    *(float4*)(avg+obase)   = s0;
    *(float4*)(avg+obase+4) = s1;
  }
}

// y_i = y_i / (y_i * (M[i,:]. x) + eps)   -- one row per block, coalesced
__global__ __launch_bounds__(256) void sink_phase(const float* __restrict__ M,
    const double* __restrict__ x, double* __restrict__ y)
{
  __shared__ double red[4];
  int i = blockIdx.x, b = blockIdx.y, tid = threadIdx.x;
  const float* row = M + ((long)b*NTOK+i)*NTOK;
  const double* xb = x + b*NTOK;
  double s=0.0;
  #pragma unroll
  for (int k=0;k<8;k++){ int j=k*256+tid; s += (double)row[j]*xb[j]; }
  s = wred_sumd(s);
  if((tid&63)==0) red[tid>>6]=s;
  __syncthreads();
  if (tid==0){
    double st = red[0]+red[1]+red[2]+red[3];
    double yi = y[b*NTOK+i];
    y[b*NTOK+i] = yi / (yi*st + EPSD);
  }
}

__global__ __launch_bounds__(256) void argmax_kernel(const float* __restrict__ P,
    const double* __restrict__ v, const int* __restrict__ perm,
    float* __restrict__ dout_perm)
{
  __shared__ double sv[4]; __shared__ int sj[4];
  int i = blockIdx.x, b = blockIdx.y, tid=threadIdx.x;
  const float* row = P + ((long)b*NTOK+i)*NTOK;
  const double* vb = v + b*NTOK;
  double bv=-1.0; int bj=0;
  #pragma unroll
  for (int k=0;k<8;k++){
    int j=k*256+tid; double val=(double)row[j]*vb[j];
    if (val>bv){bv=val;bj=j;}
  }
  for (int o=32;o;o>>=1){
    double ov=__shfl_xor(bv,o); int oj=__shfl_xor(bj,o);
    if (ov>bv || (ov==bv && oj<bj)){bv=ov;bj=oj;}
  }
  if ((tid&63)==0){ sv[tid>>6]=bv; sj[tid>>6]=bj; }
  __syncthreads();
  if (tid==0){
    for (int w=1;w<4;w++){
      if (sv[w]>bv || (sv[w]==bv && sj[w]<bj)){bv=sv[w];bj=sj[w];}
    }
    int np = perm[b*NTOK + bj];
    dout_perm[b*NTOK + i] = (float)np;
  }
}

__global__ __launch_bounds__(256) void out_kernel(
    const unsigned short* __restrict__ Ob, const unsigned short* __restrict__ Wob,
    const float* __restrict__ bo, float* __restrict__ dout)
{
  __shared__ unsigned short lds[(128+128)*32];
  int m0 = blockIdx.x*128, n0 = blockIdx.y*128;
  f32x4 acc[4][4];
  f32x4 z = {0.f,0.f,0.f,0.f};
  for (int i=0;i<4;i++) for(int j=0;j<4;j++) acc[i][j] = z;
  gemm_bt_core<128,128>(Ob + (long)m0*DMODEL, DMODEL, Wob + (long)n0*DMODEL, DMODEL,
                        DMODEL, acc, lds, lds + 128*32);
  int lane = threadIdx.x & 63, wave = threadIdx.x >> 6;
  int wm = wave>>1, wn = wave&1;
  int cr = (lane>>4)<<2, cc = lane & 15;
  for (int i=0;i<4;i++) for(int j=0;j<4;j++) for(int r=0;r<4;r++){
    int row = m0 + wm*64 + i*16 + cr + r;
    int col = n0 + wn*64 + j*16 + cc;
    dout[(long)row*DMODEL + col] = acc[i][j][r] + bo[col];
  }
}

__global__ void cert_kernel(const float* __restrict__ cert,
    const float* __restrict__ ctemp, const float* __restrict__ entb,
    float* __restrict__ dout_cert)
{
  int idx = blockIdx.x*256+threadIdx.x;
  if (idx >= BATCH*NTOK) return;
  int b = idx >> 11, row = idx & 2047;
  float s = 0.f;
  #pragma unroll
  for (int h=0; h<NHEADS; h++) s += entb[((long)(b*NHEADS+h))*NTOK + row];
  float ent = -s * (1.0f/16.0f);
  float ct = ctemp[0];
  float arg = ct * (logf((float)NTOK) - ent);
  float upd = 1.0f/(1.0f+expf(-arg));
  dout_cert[idx] = fmaxf(cert[idx], upd);
}

extern "C" void kernel_launch(void* const* d_in, const int* in_sizes, int n_in,
                              void* d_out, int out_size, void* d_ws, size_t ws_size,
                              hipStream_t stream)
{
  const float* x    = (const float*)d_in[0];
  const float* cert = (const float*)d_in[1];
  const int*   perm = (const int*)d_in[2];
  const float* Wq   = (const float*)d_in[3];
  const float* bq   = (const float*)d_in[4];
  const float* Wk   = (const float*)d_in[5];
  const float* bk   = (const float*)d_in[6];
  const float* Wv   = (const float*)d_in[7];
  const float* bv   = (const float*)d_in[8];
  const float* Wo   = (const float*)d_in[9];
  const float* bo   = (const float*)d_in[10];
  const float* psc  = (const float*)d_in[11];
  const float* ctmp = (const float*)d_in[12];
  float* dout = (float*)d_out;

  // layout: doubles, f32 arrays, bf16 region, Pbig
  double* u    = (double*)d_ws;                         // 4096
  double* v    = u + 4096;                              // 4096
  float* avg   = (float*)(v + 4096);                    // 8,388,608
  float* avgT  = avg   + 8388608;                       // 8,388,608
  float* mbuf  = avgT  + 8388608;                       // 65,536
  float* ilbuf = mbuf  + 65536;                         // 65,536
  float* entb  = ilbuf + 65536;                         // 65,536
  float* mscale= entb  + 65536;                         // 1,048,576
  unsigned short* xb  = (unsigned short*)(mscale + 1048576);  // 4,194,304
  unsigned short* Wqb = xb  + 4194304;
  unsigned short* Wkb = Wqb + 1048576;
  unsigned short* Wvb = Wkb + 1048576;
  unsigned short* Wob = Wvb + 1048576;
  unsigned short* Qb  = Wob + 1048576;                  // 4,194,304 each
  unsigned short* Kb  = Qb  + 4194304;
  unsigned short* Vb  = Kb  + 4194304;
  unsigned short* Vt  = Vb  + 4194304;
  unsigned short* Ob  = Vt  + 4194304;                  // 4,194,304
  unsigned short* Pbig= Ob  + 4194304;                  // G * 16,777,216 B

  const size_t fixedBytes = 8192*8
                          + (size_t)(8388608*2 + 65536*3 + 1048576)*4
                          + (size_t)29360128*2;         // ~130.9 MB
  int G = 16;
  while (G > 1 && fixedBytes + (size_t)G*16777216ull > ws_size) G >>= 1;

  f2b_multi<<<dim3(32768),256,0,stream>>>(x, Wq, Wk, Wv, Wo, xb);
  init_kernel<<<dim3(32),256,0,stream>>>(u);

  qkv_kernel<<<dim3(32,24),256,0,stream>>>(xb, Wqb,bq, Wkb,bk, Wvb,bv, Qb,Kb,Vb);
  vtrans_kernel<<<dim3(64,32,2), dim3(32,8),0,stream>>>(Vb, Vt);

  for (int h0=0; h0<NHEADS; h0+=G){
    attnA_kernel<<<dim3(16,G,2),512,0,stream>>>(Qb, Kb, Vt, perm, psc,
        Ob, mbuf, ilbuf, entb, mscale, Pbig, h0, G);
    attnB_kernel<<<dim3(16,16,2),256,0,stream>>>(Pbig, mscale, mbuf, ilbuf,
        avg, h0, G, (h0==0)?1:0, (h0+G>=NHEADS)?1:0);
  }

  ftrans_kernel<<<dim3(64,64,2), dim3(32,8),0,stream>>>(avg, avgT);

  for (int it=0; it<10; it++){
    sink_phase<<<dim3(2048,2),256,0,stream>>>(avg,  v, u);
    sink_phase<<<dim3(2048,2),256,0,stream>>>(avgT, u, v);
  }
  argmax_kernel<<<dim3(2048,2),256,0,stream>>>(avg, v, perm, dout + 4194304 + 4096);

  out_kernel <<<dim3(32,8),256,0,stream>>>(Ob, Wob, bo, dout);
  cert_kernel<<<dim3(16), 256,0,stream>>>(cert, ctmp, entb, dout + 4194304);
}

// Round 9
// 611.224 us; speedup vs baseline: 2.6269x; 1.0438x over previous
//
#include <hip/hip_runtime.h>
#include <cstdint>

#define NTOK 2048
#define DMODEL 1024
#define NHEADS 16
#define HD 64
#define BATCH 2
#define EPSF 1e-10f
#define EPSD 1e-10

typedef __attribute__((ext_vector_type(8))) short bf16x8;
typedef __attribute__((ext_vector_type(8))) _Float16 f16x8;
typedef __attribute__((ext_vector_type(4))) float f32x4;

__device__ __forceinline__ float bf2f(unsigned short u){
  union { unsigned int i; float f; } c; c.i = ((unsigned int)u) << 16; return c.f;
}
__device__ __forceinline__ unsigned short f2bf(float f){
  union { float f; unsigned int u; } c; c.f = f;
  unsigned int u = c.u;
  unsigned int r = (u + 0x7FFFu + ((u >> 16) & 1u)) >> 16;
  return (unsigned short)r;
}
__device__ __forceinline__ unsigned short f2h(float f){
  union { _Float16 h; unsigned short u; } c; c.h = (_Float16)f; return c.u;
}
__device__ __forceinline__ float h2f(unsigned short u){
  union { unsigned short u; _Float16 h; } c; c.u = u; return (float)c.h;
}

__device__ __forceinline__ void async16(const unsigned short* g, unsigned short* lds_base){
  __builtin_amdgcn_global_load_lds((const __attribute__((address_space(1))) unsigned int*)g,
                                   (__attribute__((address_space(3))) unsigned int*)lds_base,
                                   16, 0, 0);
}

// C[m,n] = sum_k A[m,k] * B[n,k]  (both K-major bf16), 256 threads, waves 2x2.
template<int BM, int BN>
__device__ __forceinline__ void gemm_bt_core(
    const unsigned short* A, int lda,
    const unsigned short* B, int ldb,
    int K,
    f32x4 (&acc)[BM/32][BN/32],
    unsigned short* ldsA, unsigned short* ldsB)
{
  constexpr int TM = BM/32, TN = BN/32;
  const int tid  = threadIdx.x;
  const int lane = tid & 63;
  const int wave = tid >> 6;
  const int wm = wave >> 1, wn = wave & 1;
  const int fr = lane & 15;
  const int fk = (lane >> 4) << 3;
  const int sr = lane >> 2;
  const int sk = (lane & 3) << 3;

  for (int k0 = 0; k0 < K; k0 += 32){
    #pragma unroll
    for (int c = 0; c < BM/64; c++){
      int ch = c*4 + wave;
      async16(A + (long)(ch*16 + sr)*lda + (k0 + sk), ldsA + ch*512);
    }
    #pragma unroll
    for (int c = 0; c < BN/64; c++){
      int ch = c*4 + wave;
      async16(B + (long)(ch*16 + sr)*ldb + (k0 + sk), ldsB + ch*512);
    }
    __syncthreads();
    bf16x8 af[TM], bf[TN];
    #pragma unroll
    for (int i=0;i<TM;i++)
      af[i] = *(const bf16x8*)(ldsA + ((wm*TM*16) + i*16 + fr)*32 + fk);
    #pragma unroll
    for (int j=0;j<TN;j++)
      bf[j] = *(const bf16x8*)(ldsB + ((wn*TN*16) + j*16 + fr)*32 + fk);
    #pragma unroll
    for (int i=0;i<TM;i++)
      #pragma unroll
      for (int j=0;j<TN;j++)
        acc[i][j] = __builtin_amdgcn_mfma_f32_16x16x32_bf16(af[i], bf[j], acc[i][j], 0, 0, 0);
    __syncthreads();
  }
}

__device__ __forceinline__ double wred_sumd(double x){
  for(int o=32;o;o>>=1) x+=__shfl_xor(x,o); return x;
}

// ---------------- kernels ----------------

__global__ void f2b_multi(const float* __restrict__ x,
    const float* __restrict__ wq, const float* __restrict__ wk,
    const float* __restrict__ wv, const float* __restrict__ wo,
    unsigned short* __restrict__ out)
{
  int i = blockIdx.x*256 + threadIdx.x;   // grid covers 8,388,608
  float s;
  if (i < 4194304) s = x[i];
  else {
    int d = i - 4194304;
    int r = d >> 20, off = d & 1048575;
    s = (r==0 ? wq : (r==1 ? wk : (r==2 ? wv : wo)))[off];
  }
  out[i] = f2bf(s);
}

__global__ void init_kernel(double* __restrict__ uv){
  int idx = blockIdx.x*256 + threadIdx.x;
  if (idx < 8192) uv[idx] = 1.0;     // u, v
}

__global__ __launch_bounds__(256) void qkv_kernel(
    const unsigned short* __restrict__ xb,
    const unsigned short* __restrict__ Wqb, const float* __restrict__ bq,
    const unsigned short* __restrict__ Wkb, const float* __restrict__ bk,
    const unsigned short* __restrict__ Wvb, const float* __restrict__ bv,
    unsigned short* __restrict__ Qb, unsigned short* __restrict__ Kb,
    unsigned short* __restrict__ Vb)
{
  __shared__ unsigned short lds[(128+128)*32];
  int sel = blockIdx.y >> 3;
  int n0 = (blockIdx.y & 7) * 128;
  int m0 = blockIdx.x * 128;
  const unsigned short* W = sel==0 ? Wqb : (sel==1 ? Wkb : Wvb);
  const float* bias       = sel==0 ? bq  : (sel==1 ? bk  : bv);
  unsigned short* out     = sel==0 ? Qb  : (sel==1 ? Kb  : Vb);
  f32x4 acc[4][4];
  f32x4 z = {0.f,0.f,0.f,0.f};
  for (int i=0;i<4;i++) for(int j=0;j<4;j++) acc[i][j] = z;
  gemm_bt_core<128,128>(xb + (long)m0*DMODEL, DMODEL, W + (long)n0*DMODEL, DMODEL,
                        DMODEL, acc, lds, lds + 128*32);
  int lane = threadIdx.x & 63, wave = threadIdx.x >> 6;
  int wm = wave>>1, wn = wave&1;
  int cr = (lane>>4)<<2, cc = lane & 15;
  for (int i=0;i<4;i++) for(int j=0;j<4;j++) for(int r=0;r<4;r++){
    int row = m0 + wm*64 + i*16 + cr + r;
    int col = n0 + wn*64 + j*16 + cc;
    out[(long)row*DMODEL + col] = f2bf(acc[i][j][r] + bias[col]);
  }
}

__global__ void vtrans_kernel(const unsigned short* __restrict__ Vb,
                              unsigned short* __restrict__ Vt)
{
  __shared__ unsigned short t[32][33];
  int b = blockIdx.z, i0 = blockIdx.x*32, e0 = blockIdx.y*32;
  int tx = threadIdx.x, ty = threadIdx.y;
  for (int r=0;r<32;r+=8) t[ty+r][tx] = Vb[((long)b*NTOK + i0+ty+r)*DMODEL + e0+tx];
  __syncthreads();
  for (int r=0;r<32;r+=8) Vt[((long)b*DMODEL + e0+ty+r)*NTOK + i0+tx] = t[tx][ty+r];
}

// f32 -> f16 per-batch transpose (for sinkhorn column pass)
__global__ void ftrans_kernel(const float* __restrict__ in, unsigned short* __restrict__ out){
  __shared__ float t[32][33];
  int b = blockIdx.z, i0 = blockIdx.x*32, j0 = blockIdx.y*32;
  int tx = threadIdx.x, ty = threadIdx.y;
  for (int r=0;r<32;r+=8) t[ty+r][tx] = in[((long)(b*NTOK + i0+ty+r))*NTOK + j0+tx];
  __syncthreads();
  for (int r=0;r<32;r+=8) out[((long)(b*NTOK + j0+ty+r))*NTOK + i0+tx] = f2h(t[tx][ty+r]);
}

// ---- split-K single-pass flash attention per (b,h,row-block,half).
// Each block: 128 rows, 8 of 16 key tiles. Writes partial m/l/T + unnormalized
// O (bf16) + its Pbig tiles (+ per-tile chain max mscale). 512 thr, 2 blk/CU. ----
__global__ __launch_bounds__(512,4) void attnA_kernel(
    const unsigned short* __restrict__ Qb, const unsigned short* __restrict__ Kb,
    const unsigned short* __restrict__ Vt, const int* __restrict__ perm,
    const float* __restrict__ psc,
    float* __restrict__ mpart, float* __restrict__ lpart, float* __restrict__ Tpart,
    unsigned short* __restrict__ Opart,
    float* __restrict__ mscale, unsigned short* __restrict__ Pbig,
    int h0, int gcnt)
{
  __shared__ unsigned short Kt[2*128*32];   // bf16 [kc][col][32]
  __shared__ unsigned short Vtl[64*136];    // f16  [ocol][128+pad]
  __shared__ unsigned short Pt[128*136];    // f16  [row][128+pad]
  __shared__ unsigned short pbs[2048];

  const int tid  = threadIdx.x;
  const int lane = tid & 63;
  const int wave = tid >> 6;              // 0..7, 16 rows each
  const int fr   = lane & 15;
  const int fkg  = lane >> 4;
  const int fk   = fkg << 3;
  const int cr   = fkg << 2;
  const int rw   = wave << 4;             // row base within 128-tile
  const int rt   = blockIdx.x >> 1;
  const int half = blockIdx.x & 1;
  const int m0   = rt * 128;
  const int hl   = blockIdx.y;
  const int h    = h0 + hl;
  const int b    = blockIdx.z;

  for (int i = tid; i < 2048; i += 512) pbs[i] = (unsigned short)perm[b*NTOK + i];

  bf16x8 qf[2];
  #pragma unroll
  for (int kc=0;kc<2;kc++)
    qf[kc] = *(const bf16x8*)(Qb + ((long)(b*NTOK + m0 + rw + fr))*DMODEL + h*HD + kc*32 + fk);

  const float asc = fabsf(psc[h]);
  __syncthreads();

  float prow[4];
  #pragma unroll
  for (int r=0;r<4;r++) prow[r] = (float)pbs[m0 + rw + cr + r];

  float mrow[4], lrow[4], Trow[4];
  #pragma unroll
  for (int r=0;r<4;r++){ mrow[r] = -1e30f; lrow[r] = 0.f; Trow[r] = 0.f; }
  f32x4 oacc[4];
  {
    f32x4 z = {0.f,0.f,0.f,0.f};
    for (int jj=0;jj<4;jj++) oacc[jj]=z;
  }

  for (int j2=0;j2<8;j2++){
    int j = half*8 + j2;
    __syncthreads();           // protect Kt/Vtl/Pt reuse across iterations
    #pragma unroll
    for (int c=0;c<2;c++){     // K tile: 16 chunks of (16 cols x 32 k)
      int q = c*8 + wave;
      int kc = q >> 3, rb = (q & 7) * 16;
      async16(Kb + ((long)(b*NTOK + j*128 + rb + (lane>>2)))*DMODEL + h*HD + kc*32 + ((lane&3)<<3),
              Kt + kc*4096 + rb*32);
    }
    {   // V tile: bf16 global -> f16 LDS (512 threads: 64 cols x 8 segs of 16)
      int c = tid>>3, sg = tid&7;
      const unsigned short* vg = Vt + ((long)(b*DMODEL + h*HD + c))*NTOK + j*128 + sg*16;
      unsigned short* vl = Vtl + c*136 + sg*16;
      #pragma unroll
      for (int s2=0;s2<2;s2++){
        bf16x8 vv = *(const bf16x8*)(vg + s2*8);
        unsigned short tmp[8];
        #pragma unroll
        for (int e=0;e<8;e++) tmp[e] = f2h(bf2f(((unsigned short*)&vv)[e]));
        *(uint4*)(vl + s2*8) = *(uint4*)tmp;
      }
    }
    __syncthreads();

    f32x4 sacc[8];
    {
      f32x4 z = {0.f,0.f,0.f,0.f};
      for (int jj=0;jj<8;jj++) sacc[jj]=z;
    }
    #pragma unroll
    for (int kc=0;kc<2;kc++){
      bf16x8 bfr[8];
      #pragma unroll
      for (int jj=0;jj<8;jj++) bfr[jj] = *(const bf16x8*)(Kt + kc*4096 + (jj*16+fr)*32 + fk);
      #pragma unroll
      for (int jj=0;jj<8;jj++)
        sacc[jj] = __builtin_amdgcn_mfma_f32_16x16x32_bf16(qf[kc], bfr[jj], sacc[jj],0,0,0);
    }

    float pcol[8];
    #pragma unroll
    for (int jj=0;jj<8;jj++) pcol[jj] = (float)pbs[j*128 + jj*16 + fr];

    #pragma unroll
    for (int r=0;r<4;r++){
      float sv[8];
      float tm = -1e30f;
      #pragma unroll
      for (int jj=0;jj<8;jj++){
        sv[jj] = sacc[jj][r]*0.125f - fabsf(prow[r]-pcol[jj])*asc;
        tm = fmaxf(tm, sv[jj]);
      }
      #pragma unroll
      for (int o=1;o<16;o<<=1) tm = fmaxf(tm, __shfl_xor(tm,o));
      float nm = fmaxf(mrow[r], tm);
      float alpha = expf(mrow[r] - nm);
      float lres = lrow[r]*alpha;
      Trow[r] = Trow[r]*alpha + (mrow[r]-nm)*lres;
      #pragma unroll
      for (int jc=0;jc<4;jc++) oacc[jc][r] *= alpha;
      float ts=0.f, tT=0.f;
      int prowbase = (rw + cr + r)*136;
      #pragma unroll
      for (int jj=0;jj<8;jj++){
        float d = sv[jj]-nm;
        float ev = expf(d);
        ts += ev; tT += ev*d;
        Pt[prowbase + jj*16 + fr] = f2h(ev);
      }
      #pragma unroll
      for (int o=1;o<16;o<<=1){ ts += __shfl_xor(ts,o); tT += __shfl_xor(tT,o); }
      lrow[r] = lres + ts;
      Trow[r] += tT;
      mrow[r] = nm;
      if (fr==0)
        mscale[(((long)(b*NHEADS+h))*16 + j)*NTOK + m0 + rw + cr + r] = nm;
    }
    __syncthreads();
    {   // coalesced P tile spill (f16): 512 threads x 64B
      const uint4* src = (const uint4*)(Pt + (tid>>2)*136 + (tid&3)*32);
      uint4* dst = (uint4*)(Pbig + (((long)(b*gcnt + hl)*NTOK + m0 + (tid>>2)))*NTOK + j*128 + (tid&3)*32);
      #pragma unroll
      for (int q=0;q<4;q++) dst[q] = src[q];
    }
    #pragma unroll
    for (int kp=0;kp<4;kp++){
      f16x8 paf, pbf[4];
      paf = *(const f16x8*)(Pt + (rw+fr)*136 + kp*32 + fk);
      #pragma unroll
      for (int jj=0;jj<4;jj++) pbf[jj] = *(const f16x8*)(Vtl + (jj*16+fr)*136 + kp*32 + fk);
      #pragma unroll
      for (int jj=0;jj<4;jj++)
        oacc[jj] = __builtin_amdgcn_mfma_f32_16x16x32_f16(paf, pbf[jj], oacc[jj],0,0,0);
    }
  }

  // write partials (unnormalized O, chain m/l/T)
  long pbase = ((long)(half*BATCH + b)*NHEADS + h)*NTOK;
  #pragma unroll
  for (int jj=0;jj<4;jj++)
    #pragma unroll
    for (int r=0;r<4;r++){
      int row = m0 + rw + cr + r;
      Opart[(pbase + row)*HD + jj*16 + fr] = f2bf(oacc[jj][r]);
    }
  if (fr == 0){
    #pragma unroll
    for (int r=0;r<4;r++){
      int row = m0 + rw + cr + r;
      mpart[pbase + row] = mrow[r];
      lpart[pbase + row] = lrow[r];
      Tpart[pbase + row] = Trow[r];
    }
  }
}

// ---- merge the two key-halves: O -> Ob (normalized bf16), m/il/entropy ----
__global__ __launch_bounds__(256) void merge_kernel(
    const float* __restrict__ mpart, const float* __restrict__ lpart,
    const float* __restrict__ Tpart, const unsigned short* __restrict__ Opart,
    unsigned short* __restrict__ Ob, float* __restrict__ mbuf,
    float* __restrict__ ilbuf, float* __restrict__ entb, int h0)
{
  int tid = threadIdx.x;
  int row = blockIdx.x*4 + (tid>>6);
  int h = h0 + blockIdx.y;
  int b = blockIdx.z;
  int col = tid & 63;
  long o1 = ((long)(0*BATCH + b)*NHEADS + h)*NTOK + row;
  long o2 = ((long)(1*BATCH + b)*NHEADS + h)*NTOK + row;
  float m1 = mpart[o1], m2 = mpart[o2];
  float l1 = lpart[o1], l2 = lpart[o2];
  float m = fmaxf(m1, m2);
  float e1 = expf(m1-m), e2 = expf(m2-m);
  float l = l1*e1 + l2*e2;
  float il = 1.0f/l;
  float Ov = (bf2f(Opart[o1*HD + col])*e1 + bf2f(Opart[o2*HD + col])*e2)*il;
  Ob[((long)(b*NTOK + row))*DMODEL + h*HD + col] = f2bf(Ov);
  if (col == 0){
    float T = e1*(Tpart[o1] + (m1-m)*l1) + e2*(Tpart[o2] + (m2-m)*l2);
    long off = ((long)(b*NHEADS+h))*NTOK + row;
    mbuf[off] = m; ilbuf[off] = il;
    entb[off] = T*il - logf(l);     // = sum a*ln(a)
  }
}

// ---- avg over heads from spilled P; folds the ^10 sinkhorn prep into epilogue. ----
__global__ __launch_bounds__(256) void attnB_kernel(
    const unsigned short* __restrict__ Pbig, const float* __restrict__ mscale,
    const float* __restrict__ mbuf, const float* __restrict__ ilbuf,
    float* __restrict__ avg, int h0, int gcnt, int first, int last)
{
  const int tid = threadIdx.x;
  const int j = blockIdx.x, mb = blockIdx.y, b = blockIdx.z;
  const int rsub = tid>>4, csub = (tid&15)*8;
  for (int p=0;p<8;p++){
    int row = mb*128 + p*16 + rsub;
    long obase = ((long)(b*NTOK + row))*NTOK + j*128 + csub;
    float acc[8];
    if (first){
      #pragma unroll
      for (int e=0;e<8;e++) acc[e]=0.f;
    } else {
      float4 a0 = *(const float4*)(avg+obase);
      float4 a1 = *(const float4*)(avg+obase+4);
      acc[0]=a0.x; acc[1]=a0.y; acc[2]=a0.z; acc[3]=a0.w;
      acc[4]=a1.x; acc[5]=a1.y; acc[6]=a1.z; acc[7]=a1.w;
    }
    for (int hh=0; hh<gcnt; hh++){
      int h = h0+hh;
      float mt = mscale[(((long)(b*NHEADS+h))*16 + j)*NTOK + row];
      long off = ((long)(b*NHEADS+h))*NTOK + row;
      float sc = expf(mt - mbuf[off]) * ilbuf[off];
      f16x8 pv = *(const f16x8*)(Pbig + (((long)(b*gcnt+hh)*NTOK + row))*NTOK + j*128 + csub);
      #pragma unroll
      for (int e=0;e<8;e++) acc[e] += (float)pv[e]*sc;
    }
    if (last){
      #pragma unroll
      for (int e=0;e<8;e++) acc[e] = expf(logf(acc[e]*0.0625f + EPSF)*10.0f);
    }
    float4 s0 = {acc[0],acc[1],acc[2],acc[3]};
    float4 s1 = {acc[4],acc[5],acc[6],acc[7]};
    *(float4*)(avg+obase)   = s0;
    *(float4*)(avg+obase+4) = s1;
  }
}

// y_i = y_i / (y_i * (M[i,:]. x) + eps)   -- f32 matrix (row pass)
__global__ __launch_bounds__(256) void sink_phase(const float* __restrict__ M,
    const double* __restrict__ x, double* __restrict__ y)
{
  __shared__ double red[4];
  int i = blockIdx.x, b = blockIdx.y, tid = threadIdx.x;
  const float* row = M + ((long)b*NTOK+i)*NTOK;
  const double* xb = x + b*NTOK;
  double s=0.0;
  #pragma unroll
  for (int k=0;k<8;k++){ int j=k*256+tid; s += (double)row[j]*xb[j]; }
  s = wred_sumd(s);
  if((tid&63)==0) red[tid>>6]=s;
  __syncthreads();
  if (tid==0){
    double st = red[0]+red[1]+red[2]+red[3];
    double yi = y[b*NTOK+i];
    y[b*NTOK+i] = yi / (yi*st + EPSD);
  }
}

// same but f16 matrix (column pass on transposed copy)
__global__ __launch_bounds__(256) void sink_phase_h(const unsigned short* __restrict__ M,
    const double* __restrict__ x, double* __restrict__ y)
{
  __shared__ double red[4];
  int i = blockIdx.x, b = blockIdx.y, tid = threadIdx.x;
  const unsigned short* row = M + ((long)b*NTOK+i)*NTOK;
  const double* xb = x + b*NTOK;
  double s=0.0;
  #pragma unroll
  for (int k=0;k<8;k++){ int j=k*256+tid; s += (double)h2f(row[j])*xb[j]; }
  s = wred_sumd(s);
  if((tid&63)==0) red[tid>>6]=s;
  __syncthreads();
  if (tid==0){
    double st = red[0]+red[1]+red[2]+red[3];
    double yi = y[b*NTOK+i];
    y[b*NTOK+i] = yi / (yi*st + EPSD);
  }
}

__global__ __launch_bounds__(256) void argmax_kernel(const float* __restrict__ P,
    const double* __restrict__ v, const int* __restrict__ perm,
    float* __restrict__ dout_perm)
{
  __shared__ double sv[4]; __shared__ int sj[4];
  int i = blockIdx.x, b = blockIdx.y, tid=threadIdx.x;
  const float* row = P + ((long)b*NTOK+i)*NTOK;
  const double* vb = v + b*NTOK;
  double bv=-1.0; int bj=0;
  #pragma unroll
  for (int k=0;k<8;k++){
    int j=k*256+tid; double val=(double)row[j]*vb[j];
    if (val>bv){bv=val;bj=j;}
  }
  for (int o=32;o;o>>=1){
    double ov=__shfl_xor(bv,o); int oj=__shfl_xor(bj,o);
    if (ov>bv || (ov==bv && oj<bj)){bv=ov;bj=oj;}
  }
  if ((tid&63)==0){ sv[tid>>6]=bv; sj[tid>>6]=bj; }
  __syncthreads();
  if (tid==0){
    for (int w=1;w<4;w++){
      if (sv[w]>bv || (sv[w]==bv && sj[w]<bj)){bv=sv[w];bj=sj[w];}
    }
    int np = perm[b*NTOK + bj];
    dout_perm[b*NTOK + i] = (float)np;
  }
}

__global__ __launch_bounds__(256) void out_kernel(
    const unsigned short* __restrict__ Ob, const unsigned short* __restrict__ Wob,
    const float* __restrict__ bo, float* __restrict__ dout)
{
  __shared__ unsigned short lds[(128+128)*32];
  int m0 = blockIdx.x*128, n0 = blockIdx.y*128;
  f32x4 acc[4][4];
  f32x4 z = {0.f,0.f,0.f,0.f};
  for (int i=0;i<4;i++) for(int j=0;j<4;j++) acc[i][j] = z;
  gemm_bt_core<128,128>(Ob + (long)m0*DMODEL, DMODEL, Wob + (long)n0*DMODEL, DMODEL,
                        DMODEL, acc, lds, lds + 128*32);
  int lane = threadIdx.x & 63, wave = threadIdx.x >> 6;
  int wm = wave>>1, wn = wave&1;
  int cr = (lane>>4)<<2, cc = lane & 15;
  for (int i=0;i<4;i++) for(int j=0;j<4;j++) for(int r=0;r<4;r++){
    int row = m0 + wm*64 + i*16 + cr + r;
    int col = n0 + wn*64 + j*16 + cc;
    dout[(long)row*DMODEL + col] = acc[i][j][r] + bo[col];
  }
}

__global__ void cert_kernel(const float* __restrict__ cert,
    const float* __restrict__ ctemp, const float* __restrict__ entb,
    float* __restrict__ dout_cert)
{
  int idx = blockIdx.x*256+threadIdx.x;
  if (idx >= BATCH*NTOK) return;
  int b = idx >> 11, row = idx & 2047;
  float s = 0.f;
  #pragma unroll
  for (int h=0; h<NHEADS; h++) s += entb[((long)(b*NHEADS+h))*NTOK + row];
  float ent = -s * (1.0f/16.0f);
  float ct = ctemp[0];
  float arg = ct * (logf((float)NTOK) - ent);
  float upd = 1.0f/(1.0f+expf(-arg));
  dout_cert[idx] = fmaxf(cert[idx], upd);
}

extern "C" void kernel_launch(void* const* d_in, const int* in_sizes, int n_in,
                              void* d_out, int out_size, void* d_ws, size_t ws_size,
                              hipStream_t stream)
{
  const float* x    = (const float*)d_in[0];
  const float* cert = (const float*)d_in[1];
  const int*   perm = (const int*)d_in[2];
  const float* Wq   = (const float*)d_in[3];
  const float* bq   = (const float*)d_in[4];
  const float* Wk   = (const float*)d_in[5];
  const float* bk   = (const float*)d_in[6];
  const float* Wv   = (const float*)d_in[7];
  const float* bv   = (const float*)d_in[8];
  const float* Wo   = (const float*)d_in[9];
  const float* bo   = (const float*)d_in[10];
  const float* psc  = (const float*)d_in[11];
  const float* ctmp = (const float*)d_in[12];
  float* dout = (float*)d_out;

  // layout: doubles, f32 arrays, split-K partials, bf16 region, Pbig
  double* u    = (double*)d_ws;                         // 4096
  double* v    = u + 4096;                              // 4096
  float* avg   = (float*)(v + 4096);                    // 8,388,608 f32
  unsigned short* avgT = (unsigned short*)(avg + 8388608);  // 8,388,608 f16
  float* mbuf  = (float*)(avgT + 8388608);              // 65,536
  float* ilbuf = mbuf  + 65536;                         // 65,536
  float* entb  = ilbuf + 65536;                         // 65,536
  float* mscale= entb  + 65536;                         // 1,048,576
  float* mpart = mscale+ 1048576;                       // 131,072 (2 halves)
  float* lpart = mpart + 131072;                        // 131,072
  float* Tpart = lpart + 131072;                        // 131,072
  unsigned short* Opart = (unsigned short*)(Tpart + 131072);  // 8,388,608 bf16
  unsigned short* xb  = Opart + 8388608;                // 4,194,304
  unsigned short* Wqb = xb  + 4194304;
  unsigned short* Wkb = Wqb + 1048576;
  unsigned short* Wvb = Wkb + 1048576;
  unsigned short* Wob = Wvb + 1048576;
  unsigned short* Qb  = Wob + 1048576;                  // 4,194,304 each
  unsigned short* Kb  = Qb  + 4194304;
  unsigned short* Vb  = Kb  + 4194304;
  unsigned short* Vt  = Vb  + 4194304;
  unsigned short* Ob  = Vt  + 4194304;                  // 4,194,304
  unsigned short* Pbig= Ob  + 4194304;                  // G * 16,777,216 B

  const size_t fixedBytes = 8192*8
                          + (size_t)(8388608 + 65536*3 + 1048576 + 131072*3)*4
                          + (size_t)(8388608 + 8388608 + 8388608 + 16777216 + 4194304)*2;
                          // = 132,448,256 B
  int G = 16;
  while (G > 1 && fixedBytes + (size_t)G*16777216ull > ws_size) G >>= 1;

  f2b_multi<<<dim3(32768),256,0,stream>>>(x, Wq, Wk, Wv, Wo, xb);
  init_kernel<<<dim3(32),256,0,stream>>>(u);

  qkv_kernel<<<dim3(32,24),256,0,stream>>>(xb, Wqb,bq, Wkb,bk, Wvb,bv, Qb,Kb,Vb);
  vtrans_kernel<<<dim3(64,32,2), dim3(32,8),0,stream>>>(Vb, Vt);

  for (int h0=0; h0<NHEADS; h0+=G){
    attnA_kernel<<<dim3(32,G,2),512,0,stream>>>(Qb, Kb, Vt, perm, psc,
        mpart, lpart, Tpart, Opart, mscale, Pbig, h0, G);
    merge_kernel<<<dim3(512,G,2),256,0,stream>>>(mpart, lpart, Tpart, Opart,
        Ob, mbuf, ilbuf, entb, h0);
    attnB_kernel<<<dim3(16,16,2),256,0,stream>>>(Pbig, mscale, mbuf, ilbuf,
        avg, h0, G, (h0==0)?1:0, (h0+G>=NHEADS)?1:0);
  }

  ftrans_kernel<<<dim3(64,64,2), dim3(32,8),0,stream>>>(avg, avgT);

  for (int it=0; it<10; it++){
    sink_phase  <<<dim3(2048,2),256,0,stream>>>(avg,  v, u);
    sink_phase_h<<<dim3(2048,2),256,0,stream>>>(avgT, u, v);
  }
  argmax_kernel<<<dim3(2048,2),256,0,stream>>>(avg, v, perm, dout + 4194304 + 4096);

  out_kernel <<<dim3(32,8),256,0,stream>>>(Ob, Wob, bo, dout);
  cert_kernel<<<dim3(16), 256,0,stream>>>(cert, ctmp, entb, dout + 4194304);
}

// Round 10
// 580.091 us; speedup vs baseline: 2.7679x; 1.0537x over previous
//
#include <hip/hip_runtime.h>
#include <cstdint>

#define NTOK 2048
#define DMODEL 1024
#define NHEADS 16
#define HD 64
#define BATCH 2
#define EPSF 1e-10f
#define EPSD 1e-10

typedef __attribute__((ext_vector_type(8))) short bf16x8;
typedef __attribute__((ext_vector_type(8))) _Float16 f16x8;
typedef __attribute__((ext_vector_type(4))) float f32x4;

__device__ __forceinline__ float bf2f(unsigned short u){
  union { unsigned int i; float f; } c; c.i = ((unsigned int)u) << 16; return c.f;
}
__device__ __forceinline__ unsigned short f2bf(float f){
  union { float f; unsigned int u; } c; c.f = f;
  unsigned int u = c.u;
  unsigned int r = (u + 0x7FFFu + ((u >> 16) & 1u)) >> 16;
  return (unsigned short)r;
}
__device__ __forceinline__ unsigned short f2h(float f){
  union { _Float16 h; unsigned short u; } c; c.h = (_Float16)f; return c.u;
}
__device__ __forceinline__ float h2f(unsigned short u){
  union { unsigned short u; _Float16 h; } c; c.u = u; return (float)c.h;
}

__device__ __forceinline__ void async16(const unsigned short* g, unsigned short* lds_base){
  __builtin_amdgcn_global_load_lds((const __attribute__((address_space(1))) unsigned int*)g,
                                   (__attribute__((address_space(3))) unsigned int*)lds_base,
                                   16, 0, 0);
}

// C[m,n] = sum_k A[m,k] * B[n,k]  (both K-major bf16), 256 threads, waves 2x2.
template<int BM, int BN>
__device__ __forceinline__ void gemm_bt_core(
    const unsigned short* A, int lda,
    const unsigned short* B, int ldb,
    int K,
    f32x4 (&acc)[BM/32][BN/32],
    unsigned short* ldsA, unsigned short* ldsB)
{
  constexpr int TM = BM/32, TN = BN/32;
  const int tid  = threadIdx.x;
  const int lane = tid & 63;
  const int wave = tid >> 6;
  const int wm = wave >> 1, wn = wave & 1;
  const int fr = lane & 15;
  const int fk = (lane >> 4) << 3;
  const int sr = lane >> 2;
  const int sk = (lane & 3) << 3;

  for (int k0 = 0; k0 < K; k0 += 32){
    #pragma unroll
    for (int c = 0; c < BM/64; c++){
      int ch = c*4 + wave;
      async16(A + (long)(ch*16 + sr)*lda + (k0 + sk), ldsA + ch*512);
    }
    #pragma unroll
    for (int c = 0; c < BN/64; c++){
      int ch = c*4 + wave;
      async16(B + (long)(ch*16 + sr)*ldb + (k0 + sk), ldsB + ch*512);
    }
    __syncthreads();
    bf16x8 af[TM], bf[TN];
    #pragma unroll
    for (int i=0;i<TM;i++)
      af[i] = *(const bf16x8*)(ldsA + ((wm*TM*16) + i*16 + fr)*32 + fk);
    #pragma unroll
    for (int j=0;j<TN;j++)
      bf[j] = *(const bf16x8*)(ldsB + ((wn*TN*16) + j*16 + fr)*32 + fk);
    #pragma unroll
    for (int i=0;i<TM;i++)
      #pragma unroll
      for (int j=0;j<TN;j++)
        acc[i][j] = __builtin_amdgcn_mfma_f32_16x16x32_bf16(af[i], bf[j], acc[i][j], 0, 0, 0);
    __syncthreads();
  }
}

__device__ __forceinline__ double wred_sumd(double x){
  for(int o=32;o;o>>=1) x+=__shfl_xor(x,o); return x;
}

// ---------------- kernels ----------------

__global__ void f2b_multi(const float* __restrict__ x,
    const float* __restrict__ wq, const float* __restrict__ wk,
    const float* __restrict__ wv, const float* __restrict__ wo,
    unsigned short* __restrict__ out)
{
  int i = blockIdx.x*256 + threadIdx.x;   // grid covers 8,388,608
  float s;
  if (i < 4194304) s = x[i];
  else {
    int d = i - 4194304;
    int r = d >> 20, off = d & 1048575;
    s = (r==0 ? wq : (r==1 ? wk : (r==2 ? wv : wo)))[off];
  }
  out[i] = f2bf(s);
}

__global__ void init_kernel(double* __restrict__ uv){
  int idx = blockIdx.x*256 + threadIdx.x;
  if (idx < 8192) uv[idx] = 1.0;     // u, v
}

__global__ __launch_bounds__(256) void qkv_kernel(
    const unsigned short* __restrict__ xb,
    const unsigned short* __restrict__ Wqb, const float* __restrict__ bq,
    const unsigned short* __restrict__ Wkb, const float* __restrict__ bk,
    const unsigned short* __restrict__ Wvb, const float* __restrict__ bv,
    unsigned short* __restrict__ Qb, unsigned short* __restrict__ Kb,
    unsigned short* __restrict__ Vb)
{
  __shared__ unsigned short lds[(128+128)*32];
  int sel = blockIdx.y >> 3;
  int n0 = (blockIdx.y & 7) * 128;
  int m0 = blockIdx.x * 128;
  const unsigned short* W = sel==0 ? Wqb : (sel==1 ? Wkb : Wvb);
  const float* bias       = sel==0 ? bq  : (sel==1 ? bk  : bv);
  unsigned short* out     = sel==0 ? Qb  : (sel==1 ? Kb  : Vb);
  f32x4 acc[4][4];
  f32x4 z = {0.f,0.f,0.f,0.f};
  for (int i=0;i<4;i++) for(int j=0;j<4;j++) acc[i][j] = z;
  gemm_bt_core<128,128>(xb + (long)m0*DMODEL, DMODEL, W + (long)n0*DMODEL, DMODEL,
                        DMODEL, acc, lds, lds + 128*32);
  int lane = threadIdx.x & 63, wave = threadIdx.x >> 6;
  int wm = wave>>1, wn = wave&1;
  int cr = (lane>>4)<<2, cc = lane & 15;
  for (int i=0;i<4;i++) for(int j=0;j<4;j++) for(int r=0;r<4;r++){
    int row = m0 + wm*64 + i*16 + cr + r;
    int col = n0 + wn*64 + j*16 + cc;
    out[(long)row*DMODEL + col] = f2bf(acc[i][j][r] + bias[col]);
  }
}

// V transpose, bf16 -> f16 (attnA stages V with a raw copy)
__global__ void vtrans_kernel(const unsigned short* __restrict__ Vb,
                              unsigned short* __restrict__ Vt)
{
  __shared__ unsigned short t[32][33];
  int b = blockIdx.z, i0 = blockIdx.x*32, e0 = blockIdx.y*32;
  int tx = threadIdx.x, ty = threadIdx.y;
  for (int r=0;r<32;r+=8) t[ty+r][tx] = Vb[((long)b*NTOK + i0+ty+r)*DMODEL + e0+tx];
  __syncthreads();
  for (int r=0;r<32;r+=8)
    Vt[((long)b*DMODEL + e0+ty+r)*NTOK + i0+tx] = f2h(bf2f(t[tx][ty+r]));
}

// f32 -> f16 per-batch transpose (sinkhorn column pass)
__global__ void ftrans_kernel(const float* __restrict__ in, unsigned short* __restrict__ out){
  __shared__ float t[32][33];
  int b = blockIdx.z, i0 = blockIdx.x*32, j0 = blockIdx.y*32;
  int tx = threadIdx.x, ty = threadIdx.y;
  for (int r=0;r<32;r+=8) t[ty+r][tx] = in[((long)(b*NTOK + i0+ty+r))*NTOK + j0+tx];
  __syncthreads();
  for (int r=0;r<32;r+=8) out[((long)(b*NTOK + j0+ty+r))*NTOK + i0+tx] = f2h(t[tx][ty+r]);
}

// ---- split-K single-pass flash attention per (b,h,row-block,half). ----
__global__ __launch_bounds__(512,4) void attnA_kernel(
    const unsigned short* __restrict__ Qb, const unsigned short* __restrict__ Kb,
    const unsigned short* __restrict__ Vt, const int* __restrict__ perm,
    const float* __restrict__ psc,
    float* __restrict__ mpart, float* __restrict__ lpart, float* __restrict__ Tpart,
    unsigned short* __restrict__ Opart,
    float* __restrict__ mscale, unsigned short* __restrict__ Pbig,
    int h0, int gcnt)
{
  __shared__ unsigned short Kt[2*128*32];   // bf16 [kc][col][32]
  __shared__ unsigned short Vtl[64*136];    // f16  [ocol][128+pad]
  __shared__ unsigned short Pt[128*136];    // f16  [row][128+pad]
  __shared__ unsigned short pbs[2048];

  const int tid  = threadIdx.x;
  const int lane = tid & 63;
  const int wave = tid >> 6;              // 0..7, 16 rows each
  const int fr   = lane & 15;
  const int fkg  = lane >> 4;
  const int fk   = fkg << 3;
  const int cr   = fkg << 2;
  const int rw   = wave << 4;             // row base within 128-tile
  const int rt   = blockIdx.x >> 1;
  const int half = blockIdx.x & 1;
  const int m0   = rt * 128;
  const int hl   = blockIdx.y;
  const int h    = h0 + hl;
  const int b    = blockIdx.z;

  for (int i = tid; i < 2048; i += 512) pbs[i] = (unsigned short)perm[b*NTOK + i];

  bf16x8 qf[2];
  #pragma unroll
  for (int kc=0;kc<2;kc++)
    qf[kc] = *(const bf16x8*)(Qb + ((long)(b*NTOK + m0 + rw + fr))*DMODEL + h*HD + kc*32 + fk);

  const float asc = fabsf(psc[h]);
  __syncthreads();

  float prow[4];
  #pragma unroll
  for (int r=0;r<4;r++) prow[r] = (float)pbs[m0 + rw + cr + r];

  float mrow[4], lrow[4], Trow[4];
  #pragma unroll
  for (int r=0;r<4;r++){ mrow[r] = -1e30f; lrow[r] = 0.f; Trow[r] = 0.f; }
  f32x4 oacc[4];
  {
    f32x4 z = {0.f,0.f,0.f,0.f};
    for (int jj=0;jj<4;jj++) oacc[jj]=z;
  }

  for (int j2=0;j2<8;j2++){
    int j = half*8 + j2;
    __syncthreads();           // protect Kt/Vtl/Pt reuse across iterations
    #pragma unroll
    for (int c=0;c<2;c++){     // K tile: 16 chunks of (16 cols x 32 k)
      int q = c*8 + wave;
      int kc = q >> 3, rb = (q & 7) * 16;
      async16(Kb + ((long)(b*NTOK + j*128 + rb + (lane>>2)))*DMODEL + h*HD + kc*32 + ((lane&3)<<3),
              Kt + kc*4096 + rb*32);
    }
    {   // V tile: f16 global -> f16 LDS (raw copy, no conversion)
      int c = tid>>3, sg = tid&7;
      const unsigned short* vg = Vt + ((long)(b*DMODEL + h*HD + c))*NTOK + j*128 + sg*16;
      unsigned short* vl = Vtl + c*136 + sg*16;
      *(uint4*)(vl)   = *(const uint4*)(vg);
      *(uint4*)(vl+8) = *(const uint4*)(vg+8);
    }
    __syncthreads();

    f32x4 sacc[8];
    {
      f32x4 z = {0.f,0.f,0.f,0.f};
      for (int jj=0;jj<8;jj++) sacc[jj]=z;
    }
    #pragma unroll
    for (int kc=0;kc<2;kc++){
      bf16x8 bfr[8];
      #pragma unroll
      for (int jj=0;jj<8;jj++) bfr[jj] = *(const bf16x8*)(Kt + kc*4096 + (jj*16+fr)*32 + fk);
      #pragma unroll
      for (int jj=0;jj<8;jj++)
        sacc[jj] = __builtin_amdgcn_mfma_f32_16x16x32_bf16(qf[kc], bfr[jj], sacc[jj],0,0,0);
    }

    float pcol[8];
    #pragma unroll
    for (int jj=0;jj<8;jj++) pcol[jj] = (float)pbs[j*128 + jj*16 + fr];

    #pragma unroll
    for (int r=0;r<4;r++){
      float sv[8];
      float tm = -1e30f;
      #pragma unroll
      for (int jj=0;jj<8;jj++){
        sv[jj] = sacc[jj][r]*0.125f - fabsf(prow[r]-pcol[jj])*asc;
        tm = fmaxf(tm, sv[jj]);
      }
      #pragma unroll
      for (int o=1;o<16;o<<=1) tm = fmaxf(tm, __shfl_xor(tm,o));
      float nm = fmaxf(mrow[r], tm);
      float alpha = __expf(mrow[r] - nm);
      float lres = lrow[r]*alpha;
      Trow[r] = Trow[r]*alpha + (mrow[r]-nm)*lres;
      #pragma unroll
      for (int jc=0;jc<4;jc++) oacc[jc][r] *= alpha;
      float ts=0.f, tT=0.f;
      int prowbase = (rw + cr + r)*136;
      #pragma unroll
      for (int jj=0;jj<8;jj++){
        float d = sv[jj]-nm;
        float ev = __expf(d);
        ts += ev; tT += ev*d;
        Pt[prowbase + jj*16 + fr] = f2h(ev);
      }
      #pragma unroll
      for (int o=1;o<16;o<<=1){ ts += __shfl_xor(ts,o); tT += __shfl_xor(tT,o); }
      lrow[r] = lres + ts;
      Trow[r] += tT;
      mrow[r] = nm;
      if (fr==0)
        mscale[(((long)(b*NHEADS+h))*16 + j)*NTOK + m0 + rw + cr + r] = nm;
    }
    __syncthreads();
    {   // coalesced P tile spill (f16): 512 threads x 64B
      const uint4* src = (const uint4*)(Pt + (tid>>2)*136 + (tid&3)*32);
      uint4* dst = (uint4*)(Pbig + (((long)(b*gcnt + hl)*NTOK + m0 + (tid>>2)))*NTOK + j*128 + (tid&3)*32);
      #pragma unroll
      for (int q=0;q<4;q++) dst[q] = src[q];
    }
    #pragma unroll
    for (int kp=0;kp<4;kp++){
      f16x8 paf, pbf[4];
      paf = *(const f16x8*)(Pt + (rw+fr)*136 + kp*32 + fk);
      #pragma unroll
      for (int jj=0;jj<4;jj++) pbf[jj] = *(const f16x8*)(Vtl + (jj*16+fr)*136 + kp*32 + fk);
      #pragma unroll
      for (int jj=0;jj<4;jj++)
        oacc[jj] = __builtin_amdgcn_mfma_f32_16x16x32_f16(paf, pbf[jj], oacc[jj],0,0,0);
    }
  }

  // write partials (unnormalized O, chain m/l/T)
  long pbase = ((long)(half*BATCH + b)*NHEADS + h)*NTOK;
  #pragma unroll
  for (int jj=0;jj<4;jj++)
    #pragma unroll
    for (int r=0;r<4;r++){
      int row = m0 + rw + cr + r;
      Opart[(pbase + row)*HD + jj*16 + fr] = f2bf(oacc[jj][r]);
    }
  if (fr == 0){
    #pragma unroll
    for (int r=0;r<4;r++){
      int row = m0 + rw + cr + r;
      mpart[pbase + row] = mrow[r];
      lpart[pbase + row] = lrow[r];
      Tpart[pbase + row] = Trow[r];
    }
  }
}

// ---- merge the two key-halves: O -> Ob (normalized bf16), m/il/entropy ----
__global__ __launch_bounds__(256) void merge_kernel(
    const float* __restrict__ mpart, const float* __restrict__ lpart,
    const float* __restrict__ Tpart, const unsigned short* __restrict__ Opart,
    unsigned short* __restrict__ Ob, float* __restrict__ mbuf,
    float* __restrict__ ilbuf, float* __restrict__ entb, int h0)
{
  int tid = threadIdx.x;
  int row = blockIdx.x*4 + (tid>>6);
  int h = h0 + blockIdx.y;
  int b = blockIdx.z;
  int col = tid & 63;
  long o1 = ((long)(0*BATCH + b)*NHEADS + h)*NTOK + row;
  long o2 = ((long)(1*BATCH + b)*NHEADS + h)*NTOK + row;
  float m1 = mpart[o1], m2 = mpart[o2];
  float l1 = lpart[o1], l2 = lpart[o2];
  float m = fmaxf(m1, m2);
  float e1 = __expf(m1-m), e2 = __expf(m2-m);
  float l = l1*e1 + l2*e2;
  float il = 1.0f/l;
  float Ov = (bf2f(Opart[o1*HD + col])*e1 + bf2f(Opart[o2*HD + col])*e2)*il;
  Ob[((long)(b*NTOK + row))*DMODEL + h*HD + col] = f2bf(Ov);
  if (col == 0){
    float T = e1*(Tpart[o1] + (m1-m)*l1) + e2*(Tpart[o2] + (m2-m)*l2);
    long off = ((long)(b*NHEADS+h))*NTOK + row;
    mbuf[off] = m; ilbuf[off] = il;
    entb[off] = T*il - __logf(l);     // = sum a*ln(a)
  }
}

// ---- avg over heads from spilled P; ^10 prep + f16 row-major copy in epilogue. ----
__global__ __launch_bounds__(256) void attnB_kernel(
    const unsigned short* __restrict__ Pbig, const float* __restrict__ mscale,
    const float* __restrict__ mbuf, const float* __restrict__ ilbuf,
    float* __restrict__ avg, unsigned short* __restrict__ avgH,
    int h0, int gcnt, int first, int last)
{
  const int tid = threadIdx.x;
  const int j = blockIdx.x, mb = blockIdx.y, b = blockIdx.z;
  const int rsub = tid>>4, csub = (tid&15)*8;
  for (int p=0;p<8;p++){
    int row = mb*128 + p*16 + rsub;
    long obase = ((long)(b*NTOK + row))*NTOK + j*128 + csub;
    float acc[8];
    if (first){
      #pragma unroll
      for (int e=0;e<8;e++) acc[e]=0.f;
    } else {
      float4 a0 = *(const float4*)(avg+obase);
      float4 a1 = *(const float4*)(avg+obase+4);
      acc[0]=a0.x; acc[1]=a0.y; acc[2]=a0.z; acc[3]=a0.w;
      acc[4]=a1.x; acc[5]=a1.y; acc[6]=a1.z; acc[7]=a1.w;
    }
    for (int hh=0; hh<gcnt; hh++){
      int h = h0+hh;
      float mt = mscale[(((long)(b*NHEADS+h))*16 + j)*NTOK + row];
      long off = ((long)(b*NHEADS+h))*NTOK + row;
      float sc = __expf(mt - mbuf[off]) * ilbuf[off];
      f16x8 pv = *(const f16x8*)(Pbig + (((long)(b*gcnt+hh)*NTOK + row))*NTOK + j*128 + csub);
      #pragma unroll
      for (int e=0;e<8;e++) acc[e] += (float)pv[e]*sc;
    }
    if (last){
      unsigned short h8[8];
      #pragma unroll
      for (int e=0;e<8;e++){
        acc[e] = __expf(__logf(acc[e]*0.0625f + EPSF)*10.0f);
        h8[e] = f2h(acc[e]);
      }
      *(uint4*)(avgH + obase) = *(uint4*)h8;
    }
    float4 s0 = {acc[0],acc[1],acc[2],acc[3]};
    float4 s1 = {acc[4],acc[5],acc[6],acc[7]};
    *(float4*)(avg+obase)   = s0;
    *(float4*)(avg+obase+4) = s1;
  }
}

// y_i = y_i / (y_i * (M[i,:]. x) + eps)   -- f16 matrix, coalesced rows
__global__ __launch_bounds__(256) void sink_phase_h(const unsigned short* __restrict__ M,
    const double* __restrict__ x, double* __restrict__ y)
{
  __shared__ double red[4];
  int i = blockIdx.x, b = blockIdx.y, tid = threadIdx.x;
  const unsigned short* row = M + ((long)b*NTOK+i)*NTOK;
  const double* xb = x + b*NTOK;
  double s=0.0;
  #pragma unroll
  for (int k=0;k<8;k++){ int j=k*256+tid; s += (double)h2f(row[j])*xb[j]; }
  s = wred_sumd(s);
  if((tid&63)==0) red[tid>>6]=s;
  __syncthreads();
  if (tid==0){
    double st = red[0]+red[1]+red[2]+red[3];
    double yi = y[b*NTOK+i];
    y[b*NTOK+i] = yi / (yi*st + EPSD);
  }
}

__global__ __launch_bounds__(256) void argmax_kernel(const float* __restrict__ P,
    const double* __restrict__ v, const int* __restrict__ perm,
    float* __restrict__ dout_perm)
{
  __shared__ double sv[4]; __shared__ int sj[4];
  int i = blockIdx.x, b = blockIdx.y, tid=threadIdx.x;
  const float* row = P + ((long)b*NTOK+i)*NTOK;
  const double* vb = v + b*NTOK;
  double bv=-1.0; int bj=0;
  #pragma unroll
  for (int k=0;k<8;k++){
    int j=k*256+tid; double val=(double)row[j]*vb[j];
    if (val>bv){bv=val;bj=j;}
  }
  for (int o=32;o;o>>=1){
    double ov=__shfl_xor(bv,o); int oj=__shfl_xor(bj,o);
    if (ov>bv || (ov==bv && oj<bj)){bv=ov;bj=oj;}
  }
  if ((tid&63)==0){ sv[tid>>6]=bv; sj[tid>>6]=bj; }
  __syncthreads();
  if (tid==0){
    for (int w=1;w<4;w++){
      if (sv[w]>bv || (sv[w]==bv && sj[w]<bj)){bv=sv[w];bj=sj[w];}
    }
    int np = perm[b*NTOK + bj];
    dout_perm[b*NTOK + i] = (float)np;
  }
}

__global__ __launch_bounds__(256) void out_kernel(
    const unsigned short* __restrict__ Ob, const unsigned short* __restrict__ Wob,
    const float* __restrict__ bo, float* __restrict__ dout)
{
  __shared__ unsigned short lds[(128+128)*32];
  int m0 = blockIdx.x*128, n0 = blockIdx.y*128;
  f32x4 acc[4][4];
  f32x4 z = {0.f,0.f,0.f,0.f};
  for (int i=0;i<4;i++) for(int j=0;j<4;j++) acc[i][j] = z;
  gemm_bt_core<128,128>(Ob + (long)m0*DMODEL, DMODEL, Wob + (long)n0*DMODEL, DMODEL,
                        DMODEL, acc, lds, lds + 128*32);
  int lane = threadIdx.x & 63, wave = threadIdx.x >> 6;
  int wm = wave>>1, wn = wave&1;
  int cr = (lane>>4)<<2, cc = lane & 15;
  for (int i=0;i<4;i++) for(int j=0;j<4;j++) for(int r=0;r<4;r++){
    int row = m0 + wm*64 + i*16 + cr + r;
    int col = n0 + wn*64 + j*16 + cc;
    dout[(long)row*DMODEL + col] = acc[i][j][r] + bo[col];
  }
}

__global__ void cert_kernel(const float* __restrict__ cert,
    const float* __restrict__ ctemp, const float* __restrict__ entb,
    float* __restrict__ dout_cert)
{
  int idx = blockIdx.x*256+threadIdx.x;
  if (idx >= BATCH*NTOK) return;
  int b = idx >> 11, row = idx & 2047;
  float s = 0.f;
  #pragma unroll
  for (int h=0; h<NHEADS; h++) s += entb[((long)(b*NHEADS+h))*NTOK + row];
  float ent = -s * (1.0f/16.0f);
  float ct = ctemp[0];
  float arg = ct * (logf((float)NTOK) - ent);
  float upd = 1.0f/(1.0f+expf(-arg));
  dout_cert[idx] = fmaxf(cert[idx], upd);
}

extern "C" void kernel_launch(void* const* d_in, const int* in_sizes, int n_in,
                              void* d_out, int out_size, void* d_ws, size_t ws_size,
                              hipStream_t stream)
{
  const float* x    = (const float*)d_in[0];
  const float* cert = (const float*)d_in[1];
  const int*   perm = (const int*)d_in[2];
  const float* Wq   = (const float*)d_in[3];
  const float* bq   = (const float*)d_in[4];
  const float* Wk   = (const float*)d_in[5];
  const float* bk   = (const float*)d_in[6];
  const float* Wv   = (const float*)d_in[7];
  const float* bv   = (const float*)d_in[8];
  const float* Wo   = (const float*)d_in[9];
  const float* bo   = (const float*)d_in[10];
  const float* psc  = (const float*)d_in[11];
  const float* ctmp = (const float*)d_in[12];
  float* dout = (float*)d_out;

  // layout: doubles, f32 arrays, split-K partials, bf16/f16 region, Pbig
  double* u    = (double*)d_ws;                         // 4096
  double* v    = u + 4096;                              // 4096
  float* avg   = (float*)(v + 4096);                    // 8,388,608 f32
  float* mbuf  = avg   + 8388608;                       // 65,536
  float* ilbuf = mbuf  + 65536;                         // 65,536
  float* entb  = ilbuf + 65536;                         // 65,536
  float* mscale= entb  + 65536;                         // 1,048,576
  float* mpart = mscale+ 1048576;                       // 131,072 (2 halves)
  float* lpart = mpart + 131072;                        // 131,072
  float* Tpart = lpart + 131072;                        // 131,072
  unsigned short* Opart = (unsigned short*)(Tpart + 131072);  // 8,388,608 bf16
  unsigned short* xb  = Opart + 8388608;                // 4,194,304
  unsigned short* Wqb = xb  + 4194304;
  unsigned short* Wkb = Wqb + 1048576;
  unsigned short* Wvb = Wkb + 1048576;
  unsigned short* Wob = Wvb + 1048576;
  unsigned short* Qb  = Wob + 1048576;                  // 4,194,304 each
  unsigned short* Kb  = Qb  + 4194304;
  unsigned short* Vb  = Kb  + 4194304;
  unsigned short* Vt  = Vb  + 4194304;                  // f16 after vtrans
  unsigned short* Ob  = Vt  + 4194304;                  // 4,194,304
  unsigned short* Pbig= Ob  + 4194304;                  // G * 16,777,216 B
  // overlays (regions dead by the time these are written):
  unsigned short* avgH = Qb;                            // f16 row-major, 8,388,608 el (Qb+Kb)
  unsigned short* avgT = Vb;                            // f16 transposed, 8,388,608 el (Vb+Vt)

  const size_t fixedBytes = 8192*8
                          + (size_t)(8388608 + 65536*3 + 1048576 + 131072*3)*4
                          + (size_t)(8388608 + 4194304 + 4*1048576 + 4*4194304 + 4194304)*2;
                          // = 115,671,040 B
  int G = 16;
  while (G > 1 && fixedBytes + (size_t)G*16777216ull > ws_size) G >>= 1;

  f2b_multi<<<dim3(32768),256,0,stream>>>(x, Wq, Wk, Wv, Wo, xb);
  init_kernel<<<dim3(32),256,0,stream>>>(u);

  qkv_kernel<<<dim3(32,24),256,0,stream>>>(xb, Wqb,bq, Wkb,bk, Wvb,bv, Qb,Kb,Vb);
  vtrans_kernel<<<dim3(64,32,2), dim3(32,8),0,stream>>>(Vb, Vt);

  for (int h0=0; h0<NHEADS; h0+=G){
    attnA_kernel<<<dim3(32,G,2),512,0,stream>>>(Qb, Kb, Vt, perm, psc,
        mpart, lpart, Tpart, Opart, mscale, Pbig, h0, G);
    merge_kernel<<<dim3(512,G,2),256,0,stream>>>(mpart, lpart, Tpart, Opart,
        Ob, mbuf, ilbuf, entb, h0);
    attnB_kernel<<<dim3(16,16,2),256,0,stream>>>(Pbig, mscale, mbuf, ilbuf,
        avg, avgH, h0, G, (h0==0)?1:0, (h0+G>=NHEADS)?1:0);
  }

  ftrans_kernel<<<dim3(64,64,2), dim3(32,8),0,stream>>>(avg, avgT);

  for (int it=0; it<10; it++){
    sink_phase_h<<<dim3(2048,2),256,0,stream>>>(avgH, v, u);
    sink_phase_h<<<dim3(2048,2),256,0,stream>>>(avgT, u, v);
  }
  argmax_kernel<<<dim3(2048,2),256,0,stream>>>(avg, v, perm, dout + 4194304 + 4096);

  out_kernel <<<dim3(32,8),256,0,stream>>>(Ob, Wob, bo, dout);
  cert_kernel<<<dim3(16), 256,0,stream>>>(cert, ctmp, entb, dout + 4194304);
}